// Round 12
// baseline (335.861 us; speedup 1.0000x reference)
//
#include <hip/hip_runtime.h>
#include <math.h>

#define NN 4096
#define CC 512
#define EE 131072
#define NEDGE (EE + NN)
#define HH 8
#define DCO 64
#define NC2 2097152L   // NN*CC

typedef __attribute__((ext_vector_type(8))) short bfrag;
typedef __attribute__((ext_vector_type(4))) float f32x4;
typedef __attribute__((ext_vector_type(4))) int i32x4;

__device__ __forceinline__ float bf2f(unsigned short u) {
  union { float f; unsigned int i; } x; x.i = ((unsigned int)u) << 16; return x.f;
}
__device__ __forceinline__ unsigned short f2bf(float f) {
  union { float f; unsigned int i; } x; x.f = f;
  unsigned int r = x.i + 0x7FFFu + ((x.i >> 16) & 1u);
  return (unsigned short)(r >> 16);
}
__device__ __forceinline__ unsigned short f2bf_trunc(float f) {
  union { float f; unsigned int i; } x; x.f = f;
  return (unsigned short)(x.i >> 16);
}

__device__ __forceinline__ void gld16(const unsigned short* g, unsigned short* l) {
  __builtin_amdgcn_global_load_lds(
      (__attribute__((address_space(1))) unsigned int*)g,
      (__attribute__((address_space(3))) unsigned int*)l, 16, 0, 0);
}

// Q scale: (1/8) * log2(e)  -> scores in log2 domain, softmax = exp2
#define QSC 0.18033688011112042f

// ---------------- f32 -> bf16 bulk conversion + init fusion ----------------
#define CX  2097152L
#define CWL (CX + 262144L)
#define CWR (CWL + 262144L)
#define CIW (CWR + 786432L)
#define COW (CIW + 262144L)
#define CW1 (COW + 1048576L)
#define CW2 (CW1 + 1048576L)   // 5767168 = 5632 * 1024

__global__ void cvt_all(const float* __restrict__ x, const float* __restrict__ wl,
                        const float* __restrict__ wr, const float* __restrict__ iw,
                        const float* __restrict__ ow, const float* __restrict__ w1,
                        const float* __restrict__ w2, unsigned short* __restrict__ dst,
                        int* __restrict__ cntcur, const float* __restrict__ bl,
                        const float* __restrict__ br, float* __restrict__ biasc) {
  if (blockIdx.x >= 5632) {
    int t = threadIdx.x;
    if (blockIdx.x == 5632) {
      for (int k = t; k < 8192; k += 256) cntcur[k] = 0;
    } else {
      for (int k = t; k < 512; k += 256) {
        biasc[k] = bl[k];
        biasc[512 + k] = br[k];
      }
    }
    return;
  }
  long i = ((long)blockIdx.x * 256 + threadIdx.x) * 4;
  const float* s; long o;
  if (i < CX)       { s = x;  o = i; }
  else if (i < CWL) { s = wl; o = i - CX; }
  else if (i < CWR) { s = wr; o = i - CWL; }
  else if (i < CIW) { s = iw; o = i - CWR; }
  else if (i < COW) { s = ow; o = i - CIW; }
  else if (i < CW1) { s = w1; o = i - COW; }
  else              { s = w2; o = i - CW1; }
  f32x4 v = *(const f32x4*)(s + o);
  union { unsigned long long q; unsigned short u[4]; } t;
#pragma unroll
  for (int j = 0; j < 4; j++) t.u[j] = f2bf(v[j]);
  *(unsigned long long*)(dst + i) = t.q;
}

// -------- wave-autonomous GEMM: 64-thread blocks, ZERO barriers -----------
// R6-R10 evidence: the block-wide barrier-per-K-step pins all structures at
// ~45-63us/GEMM (4 waves re-converge every ~700cy; one wave's load stall
// stalls all). Here each WAVE is its own GEMM tile (32x64), with private
// LDS (A 32x32 + B 64x32, 3 buffers = 18KB) staged via wave-private
// global_load_lds. Depth-2 counted-vmcnt pipeline per wave; no s_barrier
// anywhere -- the CU scheduler interleaves ~8 resident waves/CU freely.
// B is re-fetched per wave tile (L2-absorbed; kernel is latency-bound).
// OMODE: 0 f32 out (+split-K partial), 1 bf16 out, 2 bf16+GELU, 3 QKV scatter
template<int OMODE, bool SPLIT>
__global__ __launch_bounds__(64) void gemm_w(
    const unsigned short* __restrict__ A, const unsigned short* __restrict__ B,
    const float* __restrict__ bias, void* __restrict__ C,
    int K, int lda, int ldb, int ldc)
{
  __shared__ unsigned short As[3 * 1024];
  __shared__ unsigned short Bs[3 * 2048];
  const int l = threadIdx.x;
  const int ml = l & 15, kq = l >> 4;
  const int bm = blockIdx.y << 5, bn = blockIdx.x << 6;
  if (SPLIT) { A += (long)blockIdx.z * K; B += (long)blockIdx.z * K; }
  const float* biasp = (!SPLIT || blockIdx.z == 0) ? bias : nullptr;
  const int rq = l >> 2, cq = (l & 3) << 3;
  const unsigned short* Ag = A + (long)(bm + rq) * lda + cq;
  const unsigned short* Bg = B + (long)(bn + rq) * ldb + cq;
  const long a16 = 16L * lda, b16 = 16L * ldb;
  f32x4 acc[2][4];
#pragma unroll
  for (int mi = 0; mi < 2; mi++)
#pragma unroll
    for (int ni = 0; ni < 4; ni++) acc[mi][ni] = (f32x4){0.f, 0.f, 0.f, 0.f};
  const int nt = K >> 5;
#define STAGE_W(tt, bb) do {                                   \
    const unsigned short* sa_ = Ag + (tt) * 32;                \
    const unsigned short* sb_ = Bg + (tt) * 32;                \
    gld16(sa_,            As + (bb) * 1024 + l * 8);           \
    gld16(sa_ + a16,      As + (bb) * 1024 + 512 + l * 8);     \
    gld16(sb_,            Bs + (bb) * 2048 + l * 8);           \
    gld16(sb_ + b16,      Bs + (bb) * 2048 + 512 + l * 8);     \
    gld16(sb_ + 2 * b16,  Bs + (bb) * 2048 + 1024 + l * 8);    \
    gld16(sb_ + 3 * b16,  Bs + (bb) * 2048 + 1536 + l * 8);    \
  } while (0)
  // prologue: stage tiles 0 and 1 into buffers 0 and 1 (12 loads in flight)
  STAGE_W(0, 0);
  STAGE_W(1, 1);
  int cur = 0;
  for (int t = 0; t < nt; t++) {
    if (t + 2 < nt) {
      int sbuf = cur + 2; if (sbuf >= 3) sbuf -= 3;
      STAGE_W(t + 2, sbuf);
    }
    int fl = nt - 1 - t; if (fl > 2) fl = 2;
    if (fl == 2)      asm volatile("s_waitcnt vmcnt(12)" ::: "memory");
    else if (fl == 1) asm volatile("s_waitcnt vmcnt(6)" ::: "memory");
    else              asm volatile("s_waitcnt vmcnt(0)" ::: "memory");
    const unsigned short* Ab = As + cur * 1024;
    const unsigned short* Bb = Bs + cur * 2048;
    bfrag af[2], bf[4];
#pragma unroll
    for (int mi = 0; mi < 2; mi++)
      af[mi] = *(const bfrag*)&Ab[((mi << 4) + ml) * 32 + (kq << 3)];
#pragma unroll
    for (int ni = 0; ni < 4; ni++)
      bf[ni] = *(const bfrag*)&Bb[((ni << 4) + ml) * 32 + (kq << 3)];
#pragma unroll
    for (int mi = 0; mi < 2; mi++)
#pragma unroll
      for (int ni = 0; ni < 4; ni++)
        acc[mi][ni] = __builtin_amdgcn_mfma_f32_16x16x32_bf16(af[mi], bf[ni], acc[mi][ni], 0, 0, 0);
    cur++; if (cur == 3) cur = 0;
  }
#undef STAGE_W
#pragma unroll
  for (int ni = 0; ni < 4; ni++) {
    int col = bn + (ni << 4) + ml;
    float bb = biasp ? biasp[col] : 0.f;
#pragma unroll
    for (int mi = 0; mi < 2; mi++) {
      int row0 = bm + (mi << 4) + (kq << 2);
#pragma unroll
      for (int r = 0; r < 4; r++) {
        float v = acc[mi][ni][r] + bb;
        int row = row0 + r;
        if (OMODE == 3) {
          unsigned short* q = (unsigned short*)C;
          if (col < 512) {
            int h = col >> 6, d = col & 63;
            q[(long)h * (NN * DCO) + (long)row * DCO + d] = f2bf(v * QSC);
          } else if (col < 1024) {
            int c2 = col - 512, h = c2 >> 6, d = c2 & 63;
            q[NC2 + (long)h * (NN * DCO) + (long)row * DCO + d] = f2bf(v);
          } else {
            int c2 = col - 1024, h = c2 >> 6, d = c2 & 63;
            q[2 * NC2 + (long)h * (DCO * NN) + (long)d * NN + row] = f2bf(v);
          }
        } else if (OMODE == 0) {
          long off = (SPLIT ? (long)blockIdx.z * NC2 : 0) + (long)row * ldc + col;
          ((float*)C)[off] = v;
        } else {
          if (OMODE == 2) v = 0.5f * v * (1.f + erff(v * 0.70710678118f));
          ((unsigned short*)C)[(long)row * ldc + col] = f2bf(v);
        }
      }
    }
  }
}

// ---------------- CSR build ----------------
__global__ void count_k(const int* __restrict__ ei, int* __restrict__ cnt) {
  int e = blockIdx.x * 256 + threadIdx.x;
  if (e >= NEDGE) return;
  int d = (e < EE) ? ei[EE + e] : (e - EE);
  atomicAdd(&cnt[d], 1);
}

__global__ void scan_k(const int* __restrict__ cnt, int* __restrict__ rowptr) {
  __shared__ int s[1024];
  int t = threadIdx.x;
  int b = t * 4;
  int c0 = cnt[b], c1 = cnt[b + 1], c2 = cnt[b + 2], c3 = cnt[b + 3];
  int sum = c0 + c1 + c2 + c3;
  s[t] = sum;
  __syncthreads();
  for (int o = 1; o < 1024; o <<= 1) {
    int v = (t >= o) ? s[t - o] : 0;
    __syncthreads();
    s[t] += v;
    __syncthreads();
  }
  int ex = s[t] - sum;
  rowptr[b] = ex; rowptr[b + 1] = ex + c0;
  rowptr[b + 2] = ex + c0 + c1; rowptr[b + 3] = ex + c0 + c1 + c2;
  if (t == 1023) rowptr[4096] = ex + sum;
}

__global__ void scatter_k(const int* __restrict__ ei, const int* __restrict__ rowptr,
                          int* __restrict__ cur, int* __restrict__ order) {
  int e = blockIdx.x * 256 + threadIdx.x;
  if (e >= NEDGE) return;
  int d = (e < EE) ? ei[EE + e] : (e - EE);
  int p = atomicAdd(&cur[d], 1);
  order[rowptr[d] + p] = e;
}

// ---------------- GATv2 fused: alpha + aggregate + residual + LayerNorm ----
__global__ __launch_bounds__(256) void gat_fused(
    const unsigned short* __restrict__ xlr, const float* __restrict__ x,
    const int* __restrict__ order, const int* __restrict__ rowptr,
    const int* __restrict__ ei, const float* __restrict__ att,
    const float* __restrict__ gbias,
    const float* __restrict__ g, const float* __restrict__ be,
    float* __restrict__ of, unsigned short* __restrict__ ob)
{
  __shared__ float part[4][512];
  __shared__ float sw[4][8];
  __shared__ float sinv[8];
  __shared__ float shl[8];
  int n = blockIdx.x, t = threadIdx.x;
  int beg = rowptr[n], deg = rowptr[n + 1] - beg;
  int wave = t >> 6, lane = t & 63;
  int ch = lane << 3;
  union U8 { i32x4 v; unsigned short u[8]; };
  // dst-side features: loaded once per node
  U8 XL; XL.v = *(const i32x4*)(xlr + (long)n * 1024 + ch);
  float xl[8];
#pragma unroll
  for (int j = 0; j < 8; j++) xl[j] = bf2f(XL.u[j]);
  f32x4 t0 = *(const f32x4*)(att + ch);
  f32x4 t1 = *(const f32x4*)(att + ch + 4);
  float acc[8];
#pragma unroll
  for (int j = 0; j < 8; j++) acc[j] = 0.f;
  float se = 0.f;
  int i = wave;
  U8 X;
  if (i < deg) {
    int e = order[beg + i];
    int sn = (e < EE) ? ei[e] : (e - EE);
    X.v = *(const i32x4*)(xlr + (long)sn * 1024 + 512 + ch);
  }
  while (i < deg) {
    U8 Xc = X;
    int inext = i + 4;
    if (inext < deg) {
      int e = order[beg + inext];
      int sn = (e < EE) ? ei[e] : (e - EE);
      X.v = *(const i32x4*)(xlr + (long)sn * 1024 + 512 + ch);
    }
    float xr[8];
    float p = 0.f;
#pragma unroll
    for (int j = 0; j < 8; j++) {
      xr[j] = bf2f(Xc.u[j]);
      float v = xl[j] + xr[j];
      v = (v > 0.f) ? v : 0.2f * v;
      float tv = (j < 4) ? t0[j] : t1[j - 4];
      p += tv * v;
    }
    // reduce over the 8 lanes of this head
    p += __shfl_xor(p, 1); p += __shfl_xor(p, 2); p += __shfl_xor(p, 4);
    float ew = __expf(p);
    se += ew;
#pragma unroll
    for (int j = 0; j < 8; j++) acc[j] += ew * xr[j];
    i = inext;
  }
  *(f32x4*)&part[wave][ch]     = (f32x4){acc[0], acc[1], acc[2], acc[3]};
  *(f32x4*)&part[wave][ch + 4] = (f32x4){acc[4], acc[5], acc[6], acc[7]};
  if ((lane & 7) == 0) sw[wave][lane >> 3] = se;
  __syncthreads();
  if (t < 8) sinv[t] = 1.f / (sw[0][t] + sw[1][t] + sw[2][t] + sw[3][t]);
  __syncthreads();
  long base = (long)n * CC;
  float v0, v1;
  {
    int c = t;
    float p4 = part[0][c] + part[1][c] + part[2][c] + part[3][c];
    v0 = x[base + c] + p4 * sinv[c >> 6] + gbias[c];
  }
  {
    int c = t + 256;
    float p4 = part[0][c] + part[1][c] + part[2][c] + part[3][c];
    v1 = x[base + c] + p4 * sinv[c >> 6] + gbias[c];
  }
  // LayerNorm over the 512-channel row
  float s = v0 + v1, ss = v0 * v0 + v1 * v1;
  for (int o = 32; o > 0; o >>= 1) { s += __shfl_down(s, o); ss += __shfl_down(ss, o); }
  if (lane == 0) { shl[wave] = s; shl[4 + wave] = ss; }
  __syncthreads();
  float S = shl[0] + shl[1] + shl[2] + shl[3];
  float SS = shl[4] + shl[5] + shl[6] + shl[7];
  float mean = S * (1.f / 512.f);
  float var = SS * (1.f / 512.f) - mean * mean;
  float rs = rsqrtf(var + 1e-5f);
  float y0 = (v0 - mean) * rs * g[t] + be[t];
  float y1 = (v1 - mean) * rs * g[t + 256] + be[t + 256];
  of[base + t] = y0; of[base + t + 256] = y1;
  ob[base + t] = f2bf(y0); ob[base + t + 256] = f2bf(y1);
}

// ---------------- residual + LayerNorm (NS partials summed for b) ----------
template<int NS>
__global__ __launch_bounds__(256) void resid_ln(
    const float* __restrict__ a, const float* __restrict__ b,
    const float* __restrict__ g, const float* __restrict__ be,
    float* __restrict__ of, unsigned short* __restrict__ ob)
{
  __shared__ float sh[8];
  int row = blockIdx.x, t = threadIdx.x;
  long base = (long)row * CC;
  float b0 = 0.f, b1 = 0.f;
#pragma unroll
  for (int s = 0; s < NS; s++) {
    b0 += b[(long)s * NC2 + base + t];
    b1 += b[(long)s * NC2 + base + t + 256];
  }
  float v0 = a[base + t] + b0;
  float v1 = a[base + t + 256] + b1;
  float s = v0 + v1, ss = v0 * v0 + v1 * v1;
  for (int o = 32; o > 0; o >>= 1) { s += __shfl_down(s, o); ss += __shfl_down(ss, o); }
  int wave = t >> 6, lane = t & 63;
  if (lane == 0) { sh[wave] = s; sh[4 + wave] = ss; }
  __syncthreads();
  float S = sh[0] + sh[1] + sh[2] + sh[3];
  float SS = sh[4] + sh[5] + sh[6] + sh[7];
  float mean = S * (1.f / 512.f);
  float var = SS * (1.f / 512.f) - mean * mean;
  float rs = rsqrtf(var + 1e-5f);
  float y0 = (v0 - mean) * rs * g[t] + be[t];
  float y1 = (v1 - mean) * rs * g[t + 256] + be[t + 256];
  if (of) { of[base + t] = y0; of[base + t + 256] = y1; }
  if (ob) { ob[base + t] = f2bf(y0); ob[base + t + 256] = f2bf(y1); }
}

// ---------------- flash attention: LDS-staged K/V, split-K x4, bf16 partials
// Swapped QK^T, b64 P-store, ones-MFMA row-sum, setprio around MFMA clusters.
// P-conversion: raw v_exp_f32 + v_cvt_pk_bf16_f32 in one asm block.
__global__ __launch_bounds__(256, 4) void flash_attn(
    const unsigned short* __restrict__ qkvP, unsigned short* __restrict__ Op,
    float* __restrict__ Lp)
{
  __shared__ unsigned short QP[128 * 72];
  __shared__ unsigned short Ks[64 * 72];
  __shared__ unsigned short Vs[64 * 72];
  const int tid = threadIdx.x;
  const int wave = tid >> 6, lane = tid & 63;
  const int ml = lane & 15, kq = lane >> 4;
  const int h = blockIdx.x & 7, qt = blockIdx.x >> 3;
  const int sp = blockIdx.y;
  const int n0 = qt << 7;
  const unsigned short* Qh = qkvP + (long)h * (NN * DCO);
  const unsigned short* Kh = qkvP + NC2 + (long)h * (NN * DCO);
  const unsigned short* Vh = qkvP + 2 * NC2 + (long)h * (DCO * NN);
  {
    int r = tid >> 1, c = (tid & 1) << 5;
    const unsigned short* src = Qh + (long)(n0 + r) * DCO + c;
    unsigned short* d = &QP[r * 72 + c];
    *(i32x4*)d        = *(const i32x4*)src;
    *(i32x4*)(d + 8)  = *(const i32x4*)(src + 8);
    *(i32x4*)(d + 16) = *(const i32x4*)(src + 16);
    *(i32x4*)(d + 24) = *(const i32x4*)(src + 24);
  }
  __syncthreads();
  bfrag aq[2][2];
#pragma unroll
  for (int s = 0; s < 2; s++)
#pragma unroll
    for (int kh = 0; kh < 2; kh++)
      aq[s][kh] = *(const bfrag*)&QP[(wave * 32 + s * 16 + ml) * 72 + kh * 32 + (kq << 3)];
  bfrag ones;
#pragma unroll
  for (int j = 0; j < 8; j++) ones[j] = (short)0x3F80;
  f32x4 Oa[2][4];
  f32x4 Lc[2];
#pragma unroll
  for (int s = 0; s < 2; s++) {
    Lc[s] = (f32x4){0.f, 0.f, 0.f, 0.f};
#pragma unroll
    for (int dg = 0; dg < 4; dg++) Oa[s][dg] = (f32x4){0.f, 0.f, 0.f, 0.f};
  }
  const int r_ = tid >> 2, c_ = (tid & 3) << 4;
  const int j0 = sp << 4;
  i32x4 ka, kb, va, vb;
  {
    int k0 = j0 << 6;
    ka = *(const i32x4*)(Kh + (long)(k0 + r_) * DCO + c_);
    kb = *(const i32x4*)(Kh + (long)(k0 + r_) * DCO + c_ + 8);
    va = *(const i32x4*)(Vh + (long)r_ * NN + k0 + c_);
    vb = *(const i32x4*)(Vh + (long)r_ * NN + k0 + c_ + 8);
  }
  for (int jj = 0; jj < 16; jj++) {
    if (jj) __syncthreads();
    *(i32x4*)&Ks[r_ * 72 + c_] = ka; *(i32x4*)&Ks[r_ * 72 + c_ + 8] = kb;
    *(i32x4*)&Vs[r_ * 72 + c_] = va; *(i32x4*)&Vs[r_ * 72 + c_ + 8] = vb;
    __syncthreads();
    if (jj < 15) {
      int k0 = (j0 + jj + 1) << 6;
      ka = *(const i32x4*)(Kh + (long)(k0 + r_) * DCO + c_);
      kb = *(const i32x4*)(Kh + (long)(k0 + r_) * DCO + c_ + 8);
      va = *(const i32x4*)(Vh + (long)r_ * NN + k0 + c_);
      vb = *(const i32x4*)(Vh + (long)r_ * NN + k0 + c_ + 8);
    }
    // S^T = K * Q^T : rows kv, cols q
    f32x4 sc[2][4];
#pragma unroll
    for (int s = 0; s < 2; s++)
#pragma unroll
      for (int c = 0; c < 4; c++) sc[s][c] = (f32x4){0.f, 0.f, 0.f, 0.f};
    __builtin_amdgcn_s_setprio(1);
#pragma unroll
    for (int c = 0; c < 4; c++) {
      bfrag bk0 = *(const bfrag*)&Ks[(c * 16 + ml) * 72 + (kq << 3)];
      bfrag bk1 = *(const bfrag*)&Ks[(c * 16 + ml) * 72 + 32 + (kq << 3)];
#pragma unroll
      for (int s = 0; s < 2; s++) {
        sc[s][c] = __builtin_amdgcn_mfma_f32_16x16x32_bf16(bk0, aq[s][0], sc[s][c], 0, 0, 0);
        sc[s][c] = __builtin_amdgcn_mfma_f32_16x16x32_bf16(bk1, aq[s][1], sc[s][c], 0, 0, 0);
      }
    }
    __builtin_amdgcn_s_setprio(0);
    // raw exp2 + pack to bf16 in one asm block; store P[q][kv] as b64
#pragma unroll
    for (int s = 0; s < 2; s++) {
#pragma unroll
      for (int c = 0; c < 4; c++) {
        unsigned int w0, w1;
        float e0, e1, e2, e3;
        asm("v_exp_f32 %2, %6\n\t"
            "v_exp_f32 %3, %7\n\t"
            "v_exp_f32 %4, %8\n\t"
            "v_exp_f32 %5, %9\n\t"
            "v_cvt_pk_bf16_f32 %0, %2, %3\n\t"
            "v_cvt_pk_bf16_f32 %1, %4, %5"
            : "=v"(w0), "=v"(w1), "=&v"(e0), "=&v"(e1), "=&v"(e2), "=&v"(e3)
            : "v"(sc[s][c][0]), "v"(sc[s][c][1]), "v"(sc[s][c][2]), "v"(sc[s][c][3]));
        union { unsigned long long q; unsigned int w[2]; } u;
        u.w[0] = w0; u.w[1] = w1;
        *(unsigned long long*)&QP[(wave * 32 + s * 16 + ml) * 72 + c * 16 + (kq << 2)] = u.q;
      }
    }
    bfrag ap[2][2];
#pragma unroll
    for (int s = 0; s < 2; s++)
#pragma unroll
      for (int kh = 0; kh < 2; kh++)
        ap[s][kh] = *(const bfrag*)&QP[(wave * 32 + s * 16 + ml) * 72 + kh * 32 + (kq << 3)];
    __builtin_amdgcn_s_setprio(1);
#pragma unroll
    for (int s = 0; s < 2; s++) {
      Lc[s] = __builtin_amdgcn_mfma_f32_16x16x32_bf16(ap[s][0], ones, Lc[s], 0, 0, 0);
      Lc[s] = __builtin_amdgcn_mfma_f32_16x16x32_bf16(ap[s][1], ones, Lc[s], 0, 0, 0);
    }
#pragma unroll
    for (int dg = 0; dg < 4; dg++) {
      bfrag bv0 = *(const bfrag*)&Vs[(dg * 16 + ml) * 72 + (kq << 3)];
      bfrag bv1 = *(const bfrag*)&Vs[(dg * 16 + ml) * 72 + 32 + (kq << 3)];
#pragma unroll
      for (int s = 0; s < 2; s++) {
        Oa[s][dg] = __builtin_amdgcn_mfma_f32_16x16x32_bf16(ap[s][0], bv0, Oa[s][dg], 0, 0, 0);
        Oa[s][dg] = __builtin_amdgcn_mfma_f32_16x16x32_bf16(ap[s][1], bv1, Oa[s][dg], 0, 0, 0);
      }
    }
    __builtin_amdgcn_s_setprio(0);
  }
  long obase = (long)sp * NC2;
#pragma unroll
  for (int s = 0; s < 2; s++)
#pragma unroll
    for (int dg = 0; dg < 4; dg++)
#pragma unroll
      for (int r = 0; r < 4; r++) {
        int row = wave * 32 + s * 16 + (kq << 2) + r;
        Op[obase + (long)(n0 + row) * CC + (h << 6) + (dg << 4) + ml] = f2bf(Oa[s][dg][r]);
      }
  if (ml == 0) {
#pragma unroll
    for (int s = 0; s < 2; s++)
#pragma unroll
      for (int r = 0; r < 4; r++) {
        int row = wave * 32 + s * 16 + (kq << 2) + r;
        Lp[(long)sp * (NN * HH) + (long)(n0 + row) * HH + h] = Lc[s][r];
      }
  }
}

__global__ void flash_combine(const unsigned short* __restrict__ Op,
                              const float* __restrict__ Lp,
                              unsigned short* __restrict__ Ao) {
  int idx = blockIdx.x * 256 + threadIdx.x;
  int n = idx >> 9, c = idx & 511, h = c >> 6;
  float l = 0.f, o = 0.f;
#pragma unroll
  for (int s = 0; s < 4; s++) {
    l += Lp[(long)s * (NN * HH) + (long)n * HH + h];
    o += bf2f(Op[(long)s * NC2 + idx]);
  }
  Ao[idx] = f2bf(o / l);
}

// ---------------- host orchestration ----------------
extern "C" void kernel_launch(void* const* d_in, const int* in_sizes, int n_in,
                              void* d_out, int out_size, void* d_ws, size_t ws_size,
                              hipStream_t stream) {
  typedef unsigned short u16;
  const float* x      = (const float*)d_in[0];
  const int*   ei     = (const int*)d_in[1];
  const float* wl     = (const float*)d_in[2];
  const float* bl     = (const float*)d_in[3];
  const float* wr     = (const float*)d_in[4];
  const float* br     = (const float*)d_in[5];
  const float* att    = (const float*)d_in[6];
  const float* gat_b  = (const float*)d_in[7];
  const float* in_w   = (const float*)d_in[8];
  const float* in_b   = (const float*)d_in[9];
  const float* out_w  = (const float*)d_in[10];
  const float* out_b  = (const float*)d_in[11];
  const float* ln1g   = (const float*)d_in[12];
  const float* ln1b   = (const float*)d_in[13];
  const float* ln2g   = (const float*)d_in[14];
  const float* ln2b   = (const float*)d_in[15];
  const float* ln3g   = (const float*)d_in[16];
  const float* ln3b   = (const float*)d_in[17];
  const float* w1     = (const float*)d_in[18];
  const float* b1     = (const float*)d_in[19];
  const float* w2     = (const float*)d_in[20];
  const float* b2     = (const float*)d_in[21];

  const size_t MB = 1u << 20;
  char* w = (char*)d_ws;
  float* h_f32   = (float*)(w + 0);                  // 8MB
  float* x2_f32  = (float*)(w + 8 * MB);             // 8MB
  int*   cnt     = (int*)(w + 16 * MB);              // 16KB, then cur 16KB
  int*   cur     = cnt + 4096;
  int*   rowptr  = (int*)(w + 16 * MB + 32 * 1024);
  int*   order   = (int*)(w + 16 * MB + 64 * 1024);  // 528KB
  u16*   cvt     = (u16*)(w + 17 * MB);              // 11.5MB
  u16*   xbf     = cvt;
  u16*   wlrbf   = cvt + CX;
  u16*   inwbf   = cvt + CWR;
  u16*   outwbf  = cvt + CIW;
  u16*   w1bf    = cvt + COW;
  u16*   w2bf    = cvt + CW1;
  // phase region [29MB..93MB)
  u16*   xlr_bf  = (u16*)(w + 29 * MB);              // GAT: 8MB
  u16*   Opart   = (u16*)(w + 29 * MB);              // flash: 16MB bf16 (GAT dead)
  float* proj    = (float*)(w + 29 * MB);            // post-combine: 32MB (4 partials)
  u16*   ffn1    = (u16*)(w + 61 * MB);              // 16MB -> 77MB
  u16*   qkvP    = (u16*)(w + 93 * MB);              // 12MB: Q | K | Vt
  float* biasc   = (float*)(w + 105 * MB);           // 4KB (pre-flash only)
  float* Lpart   = (float*)(w + 105 * MB);           // 512KB (flash phase)
  u16*   Ao      = (u16*)(w + 106 * MB);             // 4MB
  u16*   actb    = (u16*)(w + 110 * MB);             // 4MB; total 114MB

  // --- conversions + init + CSR ---
  cvt_all<<<5634, 256, 0, stream>>>(x, wl, wr, in_w, out_w, w1, w2, cvt,
                                    cnt, bl, br, biasc);
  count_k<<<(NEDGE + 255) / 256, 256, 0, stream>>>(ei, cnt);
  scan_k<<<1, 1024, 0, stream>>>(cnt, rowptr);
  scatter_k<<<(NEDGE + 255) / 256, 256, 0, stream>>>(ei, rowptr, cur, order);

  // --- GATv2 (alpha + aggregate + residual + LN1 fused into one kernel) ---
  gemm_w<1, false><<<dim3(16, 128), 64, 0, stream>>>(xbf, wlrbf, biasc, xlr_bf, 512, 512, 512, 1024);
  gat_fused<<<NN, 256, 0, stream>>>(xlr_bf, x, order, rowptr, ei, att, gat_b,
                                    ln1g, ln1b, h_f32, actb);

  // --- MHA (QKV scatter fused into GEMM; staged flash, split-K x4) ---
  gemm_w<3, false><<<dim3(24, 128), 64, 0, stream>>>(actb, inwbf, in_b, qkvP, 512, 512, 512, 0);
  flash_attn<<<dim3(256, 4), 256, 0, stream>>>(qkvP, Opart, Lpart);
  flash_combine<<<(NN * CC) / 256, 256, 0, stream>>>(Opart, Lpart, Ao);
  gemm_w<0, true><<<dim3(8, 128, 2), 64, 0, stream>>>(Ao, outwbf, out_b, proj, 256, 512, 512, 512);
  resid_ln<2><<<NN, 256, 0, stream>>>(h_f32, proj, ln2g, ln2b, x2_f32, actb);

  // --- FFN ---
  gemm_w<2, false><<<dim3(32, 128), 64, 0, stream>>>(actb, w1bf, b1, ffn1, 512, 512, 512, 2048);
  gemm_w<0, true><<<dim3(8, 128, 4), 64, 0, stream>>>(ffn1, w2bf, b2, proj, 512, 2048, 2048, 512);
  resid_ln<4><<<NN, 256, 0, stream>>>(x2_f32, proj, ln3g, ln3b, (float*)d_out, nullptr);
}

// Round 13
// 318.588 us; speedup vs baseline: 1.0542x; 1.0542x over previous
//
#include <hip/hip_runtime.h>
#include <math.h>

#define NN 4096
#define CC 512
#define EE 131072
#define NEDGE (EE + NN)
#define HH 8
#define DCO 64
#define NC2 2097152L   // NN*CC

typedef __attribute__((ext_vector_type(8))) short bfrag;
typedef __attribute__((ext_vector_type(4))) float f32x4;
typedef __attribute__((ext_vector_type(4))) int i32x4;

__device__ __forceinline__ float bf2f(unsigned short u) {
  union { float f; unsigned int i; } x; x.i = ((unsigned int)u) << 16; return x.f;
}
__device__ __forceinline__ unsigned short f2bf(float f) {
  union { float f; unsigned int i; } x; x.f = f;
  unsigned int r = x.i + 0x7FFFu + ((x.i >> 16) & 1u);
  return (unsigned short)(r >> 16);
}
__device__ __forceinline__ unsigned short f2bf_trunc(float f) {
  union { float f; unsigned int i; } x; x.f = f;
  return (unsigned short)(x.i >> 16);
}

__device__ __forceinline__ void gld16(const unsigned short* g, unsigned short* l) {
  __builtin_amdgcn_global_load_lds(
      (__attribute__((address_space(1))) unsigned int*)g,
      (__attribute__((address_space(3))) unsigned int*)l, 16, 0, 0);
}

// Q scale: (1/8) * log2(e)  -> scores in log2 domain, softmax = exp2
#define QSC 0.18033688011112042f

// ---------------- f32 -> bf16 bulk conversion + init fusion ----------------
#define CX  2097152L
#define CWL (CX + 262144L)
#define CWR (CWL + 262144L)
#define CIW (CWR + 786432L)
#define COW (CIW + 262144L)
#define CW1 (COW + 1048576L)
#define CW2 (CW1 + 1048576L)   // 5767168 = 5632 * 1024

__global__ void cvt_all(const float* __restrict__ x, const float* __restrict__ wl,
                        const float* __restrict__ wr, const float* __restrict__ iw,
                        const float* __restrict__ ow, const float* __restrict__ w1,
                        const float* __restrict__ w2, unsigned short* __restrict__ dst,
                        int* __restrict__ cntcur, const float* __restrict__ bl,
                        const float* __restrict__ br, float* __restrict__ biasc) {
  if (blockIdx.x >= 5632) {
    int t = threadIdx.x;
    if (blockIdx.x == 5632) {
      for (int k = t; k < 8192; k += 256) cntcur[k] = 0;
    } else {
      for (int k = t; k < 512; k += 256) {
        biasc[k] = bl[k];
        biasc[512 + k] = br[k];
      }
    }
    return;
  }
  long i = ((long)blockIdx.x * 256 + threadIdx.x) * 4;
  const float* s; long o;
  if (i < CX)       { s = x;  o = i; }
  else if (i < CWL) { s = wl; o = i - CX; }
  else if (i < CWR) { s = wr; o = i - CWL; }
  else if (i < CIW) { s = iw; o = i - CWR; }
  else if (i < COW) { s = ow; o = i - CIW; }
  else if (i < CW1) { s = w1; o = i - COW; }
  else              { s = w2; o = i - CW1; }
  f32x4 v = *(const f32x4*)(s + o);
  union { unsigned long long q; unsigned short u[4]; } t;
#pragma unroll
  for (int j = 0; j < 4; j++) t.u[j] = f2bf(v[j]);
  *(unsigned long long*)(dst + i) = t.q;
}

// ------- 64x64 bf16 GEMM: 2-wave blocks, dbuf + counted vmcnt + RAW barrier
// R6-R11 ledger: only levers that moved GEMMs were more blocks (R6 FFN1) and
// counted-vmcnt (R9, best). Here: halve block to 2 waves / 64x64 tile ->
// 2x block count (scheduling independence, half-width barriers), keep the
// R9 pipeline: stage tile t+1 (4 gld16/thread), wait vmcnt(4) (tile t only),
// raw s_barrier (no drain).
// OMODE: 0 f32 out (+split-K partial), 1 bf16 out, 2 bf16+GELU, 3 QKV scatter
template<int OMODE, bool SPLIT>
__global__ __launch_bounds__(128) void gemm_t(
    const unsigned short* __restrict__ A, const unsigned short* __restrict__ B,
    const float* __restrict__ bias, void* __restrict__ C,
    int K, int lda, int ldb, int ldc)
{
  __shared__ unsigned short As[2 * 2048];
  __shared__ unsigned short Bs[2 * 2048];
  const int tid = threadIdx.x;
  const int wave = tid >> 6, lane = tid & 63;
  const int ml = lane & 15, kq = lane >> 4;
  const int bm = blockIdx.y << 6, bn = blockIdx.x << 6;
  const int srow = tid >> 2, scol = (tid & 3) << 3;   // rows 0..31, col 0..24
  if (SPLIT) { A += (long)blockIdx.z * K; B += (long)blockIdx.z * K; }
  const float* biasp = (!SPLIT || blockIdx.z == 0) ? bias : nullptr;
  const unsigned short* Ag = A + (long)(bm + srow) * lda + scol;
  const unsigned short* Bg = B + (long)(bn + srow) * ldb + scol;
  const long a32 = 32L * lda, b32 = 32L * ldb;
  f32x4 acc[2][4];
#pragma unroll
  for (int mi = 0; mi < 2; mi++)
#pragma unroll
    for (int ni = 0; ni < 4; ni++) acc[mi][ni] = (f32x4){0.f, 0.f, 0.f, 0.f};
  const int nt = K >> 5;
  // prologue: stage tile 0 into buffer 0 (4 loads/thread)
  gld16(Ag,       As + tid * 8);
  gld16(Ag + a32, As + 1024 + tid * 8);
  gld16(Bg,       Bs + tid * 8);
  gld16(Bg + b32, Bs + 1024 + tid * 8);
  Ag += 32; Bg += 32;
  for (int t = 0; t < nt; t++) {
    const int cur = t & 1, nxt = cur ^ 1;
    if (t + 1 < nt) {
      gld16(Ag,       As + nxt * 2048 + tid * 8);
      gld16(Ag + a32, As + nxt * 2048 + 1024 + tid * 8);
      gld16(Bg,       Bs + nxt * 2048 + tid * 8);
      gld16(Bg + b32, Bs + nxt * 2048 + 1024 + tid * 8);
      Ag += 32; Bg += 32;
      asm volatile("s_waitcnt vmcnt(4)" ::: "memory");  // tile t's loads only
    } else {
      asm volatile("s_waitcnt vmcnt(0)" ::: "memory");
    }
    __builtin_amdgcn_s_barrier();   // raw: no vmcnt(0) drain
    const unsigned short* Ab = As + cur * 2048;
    const unsigned short* Bb = Bs + cur * 2048;
    bfrag af[2], bf[4];
#pragma unroll
    for (int mi = 0; mi < 2; mi++)
      af[mi] = *(const bfrag*)&Ab[((wave << 5) + (mi << 4) + ml) * 32 + (kq << 3)];
#pragma unroll
    for (int ni = 0; ni < 4; ni++)
      bf[ni] = *(const bfrag*)&Bb[((ni << 4) + ml) * 32 + (kq << 3)];
#pragma unroll
    for (int mi = 0; mi < 2; mi++)
#pragma unroll
      for (int ni = 0; ni < 4; ni++)
        acc[mi][ni] = __builtin_amdgcn_mfma_f32_16x16x32_bf16(af[mi], bf[ni], acc[mi][ni], 0, 0, 0);
    __builtin_amdgcn_s_barrier();   // readers done before buf[cur] overwrite
  }
#pragma unroll
  for (int ni = 0; ni < 4; ni++) {
    int col = bn + (ni << 4) + ml;
    float bb = biasp ? biasp[col] : 0.f;
#pragma unroll
    for (int mi = 0; mi < 2; mi++) {
      int row0 = bm + (wave << 5) + (mi << 4) + (kq << 2);
#pragma unroll
      for (int r = 0; r < 4; r++) {
        float v = acc[mi][ni][r] + bb;
        int row = row0 + r;
        if (OMODE == 3) {
          unsigned short* q = (unsigned short*)C;
          if (col < 512) {
            int h = col >> 6, d = col & 63;
            q[(long)h * (NN * DCO) + (long)row * DCO + d] = f2bf(v * QSC);
          } else if (col < 1024) {
            int c2 = col - 512, h = c2 >> 6, d = c2 & 63;
            q[NC2 + (long)h * (NN * DCO) + (long)row * DCO + d] = f2bf(v);
          } else {
            int c2 = col - 1024, h = c2 >> 6, d = c2 & 63;
            q[2 * NC2 + (long)h * (DCO * NN) + (long)d * NN + row] = f2bf(v);
          }
        } else if (OMODE == 0) {
          long off = (SPLIT ? (long)blockIdx.z * NC2 : 0) + (long)row * ldc + col;
          ((float*)C)[off] = v;
        } else {
          if (OMODE == 2) v = 0.5f * v * (1.f + erff(v * 0.70710678118f));
          ((unsigned short*)C)[(long)row * ldc + col] = f2bf(v);
        }
      }
    }
  }
}

// ---------------- CSR build ----------------
__global__ void count_k(const int* __restrict__ ei, int* __restrict__ cnt) {
  int e = blockIdx.x * 256 + threadIdx.x;
  if (e >= NEDGE) return;
  int d = (e < EE) ? ei[EE + e] : (e - EE);
  atomicAdd(&cnt[d], 1);
}

__global__ void scan_k(const int* __restrict__ cnt, int* __restrict__ rowptr) {
  __shared__ int s[1024];
  int t = threadIdx.x;
  int b = t * 4;
  int c0 = cnt[b], c1 = cnt[b + 1], c2 = cnt[b + 2], c3 = cnt[b + 3];
  int sum = c0 + c1 + c2 + c3;
  s[t] = sum;
  __syncthreads();
  for (int o = 1; o < 1024; o <<= 1) {
    int v = (t >= o) ? s[t - o] : 0;
    __syncthreads();
    s[t] += v;
    __syncthreads();
  }
  int ex = s[t] - sum;
  rowptr[b] = ex; rowptr[b + 1] = ex + c0;
  rowptr[b + 2] = ex + c0 + c1; rowptr[b + 3] = ex + c0 + c1 + c2;
  if (t == 1023) rowptr[4096] = ex + sum;
}

__global__ void scatter_k(const int* __restrict__ ei, const int* __restrict__ rowptr,
                          int* __restrict__ cur, int* __restrict__ order) {
  int e = blockIdx.x * 256 + threadIdx.x;
  if (e >= NEDGE) return;
  int d = (e < EE) ? ei[EE + e] : (e - EE);
  int p = atomicAdd(&cur[d], 1);
  order[rowptr[d] + p] = e;
}

// ---------------- GATv2 fused: alpha + aggregate + residual + LayerNorm ----
__global__ __launch_bounds__(256) void gat_fused(
    const unsigned short* __restrict__ xlr, const float* __restrict__ x,
    const int* __restrict__ order, const int* __restrict__ rowptr,
    const int* __restrict__ ei, const float* __restrict__ att,
    const float* __restrict__ gbias,
    const float* __restrict__ g, const float* __restrict__ be,
    float* __restrict__ of, unsigned short* __restrict__ ob)
{
  __shared__ float part[4][512];
  __shared__ float sw[4][8];
  __shared__ float sinv[8];
  __shared__ float shl[8];
  int n = blockIdx.x, t = threadIdx.x;
  int beg = rowptr[n], deg = rowptr[n + 1] - beg;
  int wave = t >> 6, lane = t & 63;
  int ch = lane << 3;
  union U8 { i32x4 v; unsigned short u[8]; };
  // dst-side features: loaded once per node
  U8 XL; XL.v = *(const i32x4*)(xlr + (long)n * 1024 + ch);
  float xl[8];
#pragma unroll
  for (int j = 0; j < 8; j++) xl[j] = bf2f(XL.u[j]);
  f32x4 t0 = *(const f32x4*)(att + ch);
  f32x4 t1 = *(const f32x4*)(att + ch + 4);
  float acc[8];
#pragma unroll
  for (int j = 0; j < 8; j++) acc[j] = 0.f;
  float se = 0.f;
  int i = wave;
  U8 X;
  if (i < deg) {
    int e = order[beg + i];
    int sn = (e < EE) ? ei[e] : (e - EE);
    X.v = *(const i32x4*)(xlr + (long)sn * 1024 + 512 + ch);
  }
  while (i < deg) {
    U8 Xc = X;
    int inext = i + 4;
    if (inext < deg) {
      int e = order[beg + inext];
      int sn = (e < EE) ? ei[e] : (e - EE);
      X.v = *(const i32x4*)(xlr + (long)sn * 1024 + 512 + ch);
    }
    float xr[8];
    float p = 0.f;
#pragma unroll
    for (int j = 0; j < 8; j++) {
      xr[j] = bf2f(Xc.u[j]);
      float v = xl[j] + xr[j];
      v = (v > 0.f) ? v : 0.2f * v;
      float tv = (j < 4) ? t0[j] : t1[j - 4];
      p += tv * v;
    }
    // reduce over the 8 lanes of this head
    p += __shfl_xor(p, 1); p += __shfl_xor(p, 2); p += __shfl_xor(p, 4);
    float ew = __expf(p);
    se += ew;
#pragma unroll
    for (int j = 0; j < 8; j++) acc[j] += ew * xr[j];
    i = inext;
  }
  *(f32x4*)&part[wave][ch]     = (f32x4){acc[0], acc[1], acc[2], acc[3]};
  *(f32x4*)&part[wave][ch + 4] = (f32x4){acc[4], acc[5], acc[6], acc[7]};
  if ((lane & 7) == 0) sw[wave][lane >> 3] = se;
  __syncthreads();
  if (t < 8) sinv[t] = 1.f / (sw[0][t] + sw[1][t] + sw[2][t] + sw[3][t]);
  __syncthreads();
  long base = (long)n * CC;
  float v0, v1;
  {
    int c = t;
    float p4 = part[0][c] + part[1][c] + part[2][c] + part[3][c];
    v0 = x[base + c] + p4 * sinv[c >> 6] + gbias[c];
  }
  {
    int c = t + 256;
    float p4 = part[0][c] + part[1][c] + part[2][c] + part[3][c];
    v1 = x[base + c] + p4 * sinv[c >> 6] + gbias[c];
  }
  // LayerNorm over the 512-channel row
  float s = v0 + v1, ss = v0 * v0 + v1 * v1;
  for (int o = 32; o > 0; o >>= 1) { s += __shfl_down(s, o); ss += __shfl_down(ss, o); }
  if (lane == 0) { shl[wave] = s; shl[4 + wave] = ss; }
  __syncthreads();
  float S = shl[0] + shl[1] + shl[2] + shl[3];
  float SS = shl[4] + shl[5] + shl[6] + shl[7];
  float mean = S * (1.f / 512.f);
  float var = SS * (1.f / 512.f) - mean * mean;
  float rs = rsqrtf(var + 1e-5f);
  float y0 = (v0 - mean) * rs * g[t] + be[t];
  float y1 = (v1 - mean) * rs * g[t + 256] + be[t + 256];
  of[base + t] = y0; of[base + t + 256] = y1;
  ob[base + t] = f2bf(y0); ob[base + t + 256] = f2bf(y1);
}

// ---------------- residual + LayerNorm (NS partials summed for b) ----------
template<int NS>
__global__ __launch_bounds__(256) void resid_ln(
    const float* __restrict__ a, const float* __restrict__ b,
    const float* __restrict__ g, const float* __restrict__ be,
    float* __restrict__ of, unsigned short* __restrict__ ob)
{
  __shared__ float sh[8];
  int row = blockIdx.x, t = threadIdx.x;
  long base = (long)row * CC;
  float b0 = 0.f, b1 = 0.f;
#pragma unroll
  for (int s = 0; s < NS; s++) {
    b0 += b[(long)s * NC2 + base + t];
    b1 += b[(long)s * NC2 + base + t + 256];
  }
  float v0 = a[base + t] + b0;
  float v1 = a[base + t + 256] + b1;
  float s = v0 + v1, ss = v0 * v0 + v1 * v1;
  for (int o = 32; o > 0; o >>= 1) { s += __shfl_down(s, o); ss += __shfl_down(ss, o); }
  int wave = t >> 6, lane = t & 63;
  if (lane == 0) { sh[wave] = s; sh[4 + wave] = ss; }
  __syncthreads();
  float S = sh[0] + sh[1] + sh[2] + sh[3];
  float SS = sh[4] + sh[5] + sh[6] + sh[7];
  float mean = S * (1.f / 512.f);
  float var = SS * (1.f / 512.f) - mean * mean;
  float rs = rsqrtf(var + 1e-5f);
  float y0 = (v0 - mean) * rs * g[t] + be[t];
  float y1 = (v1 - mean) * rs * g[t + 256] + be[t + 256];
  if (of) { of[base + t] = y0; of[base + t + 256] = y1; }
  if (ob) { ob[base + t] = f2bf(y0); ob[base + t + 256] = f2bf(y1); }
}

// ---------------- flash attention: LDS-staged K/V, split-K x4, bf16 partials
// Swapped QK^T, b64 P-store, ones-MFMA row-sum, setprio around MFMA clusters.
// P-conversion: raw v_exp_f32 + v_cvt_pk_bf16_f32 in one asm block.
__global__ __launch_bounds__(256, 4) void flash_attn(
    const unsigned short* __restrict__ qkvP, unsigned short* __restrict__ Op,
    float* __restrict__ Lp)
{
  __shared__ unsigned short QP[128 * 72];
  __shared__ unsigned short Ks[64 * 72];
  __shared__ unsigned short Vs[64 * 72];
  const int tid = threadIdx.x;
  const int wave = tid >> 6, lane = tid & 63;
  const int ml = lane & 15, kq = lane >> 4;
  const int h = blockIdx.x & 7, qt = blockIdx.x >> 3;
  const int sp = blockIdx.y;
  const int n0 = qt << 7;
  const unsigned short* Qh = qkvP + (long)h * (NN * DCO);
  const unsigned short* Kh = qkvP + NC2 + (long)h * (NN * DCO);
  const unsigned short* Vh = qkvP + 2 * NC2 + (long)h * (DCO * NN);
  {
    int r = tid >> 1, c = (tid & 1) << 5;
    const unsigned short* src = Qh + (long)(n0 + r) * DCO + c;
    unsigned short* d = &QP[r * 72 + c];
    *(i32x4*)d        = *(const i32x4*)src;
    *(i32x4*)(d + 8)  = *(const i32x4*)(src + 8);
    *(i32x4*)(d + 16) = *(const i32x4*)(src + 16);
    *(i32x4*)(d + 24) = *(const i32x4*)(src + 24);
  }
  __syncthreads();
  bfrag aq[2][2];
#pragma unroll
  for (int s = 0; s < 2; s++)
#pragma unroll
    for (int kh = 0; kh < 2; kh++)
      aq[s][kh] = *(const bfrag*)&QP[(wave * 32 + s * 16 + ml) * 72 + kh * 32 + (kq << 3)];
  bfrag ones;
#pragma unroll
  for (int j = 0; j < 8; j++) ones[j] = (short)0x3F80;
  f32x4 Oa[2][4];
  f32x4 Lc[2];
#pragma unroll
  for (int s = 0; s < 2; s++) {
    Lc[s] = (f32x4){0.f, 0.f, 0.f, 0.f};
#pragma unroll
    for (int dg = 0; dg < 4; dg++) Oa[s][dg] = (f32x4){0.f, 0.f, 0.f, 0.f};
  }
  const int r_ = tid >> 2, c_ = (tid & 3) << 4;
  const int j0 = sp << 4;
  i32x4 ka, kb, va, vb;
  {
    int k0 = j0 << 6;
    ka = *(const i32x4*)(Kh + (long)(k0 + r_) * DCO + c_);
    kb = *(const i32x4*)(Kh + (long)(k0 + r_) * DCO + c_ + 8);
    va = *(const i32x4*)(Vh + (long)r_ * NN + k0 + c_);
    vb = *(const i32x4*)(Vh + (long)r_ * NN + k0 + c_ + 8);
  }
  for (int jj = 0; jj < 16; jj++) {
    if (jj) __syncthreads();
    *(i32x4*)&Ks[r_ * 72 + c_] = ka; *(i32x4*)&Ks[r_ * 72 + c_ + 8] = kb;
    *(i32x4*)&Vs[r_ * 72 + c_] = va; *(i32x4*)&Vs[r_ * 72 + c_ + 8] = vb;
    __syncthreads();
    if (jj < 15) {
      int k0 = (j0 + jj + 1) << 6;
      ka = *(const i32x4*)(Kh + (long)(k0 + r_) * DCO + c_);
      kb = *(const i32x4*)(Kh + (long)(k0 + r_) * DCO + c_ + 8);
      va = *(const i32x4*)(Vh + (long)r_ * NN + k0 + c_);
      vb = *(const i32x4*)(Vh + (long)r_ * NN + k0 + c_ + 8);
    }
    // S^T = K * Q^T : rows kv, cols q
    f32x4 sc[2][4];
#pragma unroll
    for (int s = 0; s < 2; s++)
#pragma unroll
      for (int c = 0; c < 4; c++) sc[s][c] = (f32x4){0.f, 0.f, 0.f, 0.f};
    __builtin_amdgcn_s_setprio(1);
#pragma unroll
    for (int c = 0; c < 4; c++) {
      bfrag bk0 = *(const bfrag*)&Ks[(c * 16 + ml) * 72 + (kq << 3)];
      bfrag bk1 = *(const bfrag*)&Ks[(c * 16 + ml) * 72 + 32 + (kq << 3)];
#pragma unroll
      for (int s = 0; s < 2; s++) {
        sc[s][c] = __builtin_amdgcn_mfma_f32_16x16x32_bf16(bk0, aq[s][0], sc[s][c], 0, 0, 0);
        sc[s][c] = __builtin_amdgcn_mfma_f32_16x16x32_bf16(bk1, aq[s][1], sc[s][c], 0, 0, 0);
      }
    }
    __builtin_amdgcn_s_setprio(0);
    // raw exp2 + pack to bf16 in one asm block; store P[q][kv] as b64
#pragma unroll
    for (int s = 0; s < 2; s++) {
#pragma unroll
      for (int c = 0; c < 4; c++) {
        unsigned int w0, w1;
        float e0, e1, e2, e3;
        asm("v_exp_f32 %2, %6\n\t"
            "v_exp_f32 %3, %7\n\t"
            "v_exp_f32 %4, %8\n\t"
            "v_exp_f32 %5, %9\n\t"
            "v_cvt_pk_bf16_f32 %0, %2, %3\n\t"
            "v_cvt_pk_bf16_f32 %1, %4, %5"
            : "=v"(w0), "=v"(w1), "=&v"(e0), "=&v"(e1), "=&v"(e2), "=&v"(e3)
            : "v"(sc[s][c][0]), "v"(sc[s][c][1]), "v"(sc[s][c][2]), "v"(sc[s][c][3]));
        union { unsigned long long q; unsigned int w[2]; } u;
        u.w[0] = w0; u.w[1] = w1;
        *(unsigned long long*)&QP[(wave * 32 + s * 16 + ml) * 72 + c * 16 + (kq << 2)] = u.q;
      }
    }
    bfrag ap[2][2];
#pragma unroll
    for (int s = 0; s < 2; s++)
#pragma unroll
      for (int kh = 0; kh < 2; kh++)
        ap[s][kh] = *(const bfrag*)&QP[(wave * 32 + s * 16 + ml) * 72 + kh * 32 + (kq << 3)];
    __builtin_amdgcn_s_setprio(1);
#pragma unroll
    for (int s = 0; s < 2; s++) {
      Lc[s] = __builtin_amdgcn_mfma_f32_16x16x32_bf16(ap[s][0], ones, Lc[s], 0, 0, 0);
      Lc[s] = __builtin_amdgcn_mfma_f32_16x16x32_bf16(ap[s][1], ones, Lc[s], 0, 0, 0);
    }
#pragma unroll
    for (int dg = 0; dg < 4; dg++) {
      bfrag bv0 = *(const bfrag*)&Vs[(dg * 16 + ml) * 72 + (kq << 3)];
      bfrag bv1 = *(const bfrag*)&Vs[(dg * 16 + ml) * 72 + 32 + (kq << 3)];
#pragma unroll
      for (int s = 0; s < 2; s++) {
        Oa[s][dg] = __builtin_amdgcn_mfma_f32_16x16x32_bf16(ap[s][0], bv0, Oa[s][dg], 0, 0, 0);
        Oa[s][dg] = __builtin_amdgcn_mfma_f32_16x16x32_bf16(ap[s][1], bv1, Oa[s][dg], 0, 0, 0);
      }
    }
    __builtin_amdgcn_s_setprio(0);
  }
  long obase = (long)sp * NC2;
#pragma unroll
  for (int s = 0; s < 2; s++)
#pragma unroll
    for (int dg = 0; dg < 4; dg++)
#pragma unroll
      for (int r = 0; r < 4; r++) {
        int row = wave * 32 + s * 16 + (kq << 2) + r;
        Op[obase + (long)(n0 + row) * CC + (h << 6) + (dg << 4) + ml] = f2bf(Oa[s][dg][r]);
      }
  if (ml == 0) {
#pragma unroll
    for (int s = 0; s < 2; s++)
#pragma unroll
      for (int r = 0; r < 4; r++) {
        int row = wave * 32 + s * 16 + (kq << 2) + r;
        Lp[(long)sp * (NN * HH) + (long)(n0 + row) * HH + h] = Lc[s][r];
      }
  }
}

__global__ void flash_combine(const unsigned short* __restrict__ Op,
                              const float* __restrict__ Lp,
                              unsigned short* __restrict__ Ao) {
  int idx = blockIdx.x * 256 + threadIdx.x;
  int n = idx >> 9, c = idx & 511, h = c >> 6;
  float l = 0.f, o = 0.f;
#pragma unroll
  for (int s = 0; s < 4; s++) {
    l += Lp[(long)s * (NN * HH) + (long)n * HH + h];
    o += bf2f(Op[(long)s * NC2 + idx]);
  }
  Ao[idx] = f2bf(o / l);
}

// ---------------- host orchestration ----------------
extern "C" void kernel_launch(void* const* d_in, const int* in_sizes, int n_in,
                              void* d_out, int out_size, void* d_ws, size_t ws_size,
                              hipStream_t stream) {
  typedef unsigned short u16;
  const float* x      = (const float*)d_in[0];
  const int*   ei     = (const int*)d_in[1];
  const float* wl     = (const float*)d_in[2];
  const float* bl     = (const float*)d_in[3];
  const float* wr     = (const float*)d_in[4];
  const float* br     = (const float*)d_in[5];
  const float* att    = (const float*)d_in[6];
  const float* gat_b  = (const float*)d_in[7];
  const float* in_w   = (const float*)d_in[8];
  const float* in_b   = (const float*)d_in[9];
  const float* out_w  = (const float*)d_in[10];
  const float* out_b  = (const float*)d_in[11];
  const float* ln1g   = (const float*)d_in[12];
  const float* ln1b   = (const float*)d_in[13];
  const float* ln2g   = (const float*)d_in[14];
  const float* ln2b   = (const float*)d_in[15];
  const float* ln3g   = (const float*)d_in[16];
  const float* ln3b   = (const float*)d_in[17];
  const float* w1     = (const float*)d_in[18];
  const float* b1     = (const float*)d_in[19];
  const float* w2     = (const float*)d_in[20];
  const float* b2     = (const float*)d_in[21];

  const size_t MB = 1u << 20;
  char* w = (char*)d_ws;
  float* h_f32   = (float*)(w + 0);                  // 8MB
  float* x2_f32  = (float*)(w + 8 * MB);             // 8MB
  int*   cnt     = (int*)(w + 16 * MB);              // 16KB, then cur 16KB
  int*   cur     = cnt + 4096;
  int*   rowptr  = (int*)(w + 16 * MB + 32 * 1024);
  int*   order   = (int*)(w + 16 * MB + 64 * 1024);  // 528KB
  u16*   cvt     = (u16*)(w + 17 * MB);              // 11.5MB
  u16*   xbf     = cvt;
  u16*   wlrbf   = cvt + CX;
  u16*   inwbf   = cvt + CWR;
  u16*   outwbf  = cvt + CIW;
  u16*   w1bf    = cvt + COW;
  u16*   w2bf    = cvt + CW1;
  // phase region [29MB..93MB)
  u16*   xlr_bf  = (u16*)(w + 29 * MB);              // GAT: 8MB
  u16*   Opart   = (u16*)(w + 29 * MB);              // flash: 16MB bf16 (GAT dead)
  float* proj    = (float*)(w + 29 * MB);            // post-combine: 32MB (4 partials)
  u16*   ffn1    = (u16*)(w + 61 * MB);              // 16MB -> 77MB
  u16*   qkvP    = (u16*)(w + 93 * MB);              // 12MB: Q | K | Vt
  float* biasc   = (float*)(w + 105 * MB);           // 4KB (pre-flash only)
  float* Lpart   = (float*)(w + 105 * MB);           // 512KB (flash phase)
  u16*   Ao      = (u16*)(w + 106 * MB);             // 4MB
  u16*   actb    = (u16*)(w + 110 * MB);             // 4MB; total 114MB

  // --- conversions + init + CSR ---
  cvt_all<<<5634, 256, 0, stream>>>(x, wl, wr, in_w, out_w, w1, w2, cvt,
                                    cnt, bl, br, biasc);
  count_k<<<(NEDGE + 255) / 256, 256, 0, stream>>>(ei, cnt);
  scan_k<<<1, 1024, 0, stream>>>(cnt, rowptr);
  scatter_k<<<(NEDGE + 255) / 256, 256, 0, stream>>>(ei, rowptr, cur, order);

  // --- GATv2 (alpha + aggregate + residual + LN1 fused into one kernel) ---
  gemm_t<1, false><<<dim3(16, 64), 128, 0, stream>>>(xbf, wlrbf, biasc, xlr_bf, 512, 512, 512, 1024);
  gat_fused<<<NN, 256, 0, stream>>>(xlr_bf, x, order, rowptr, ei, att, gat_b,
                                    ln1g, ln1b, h_f32, actb);

  // --- MHA (QKV scatter fused into GEMM; staged flash, split-K x4) ---
  gemm_t<3, false><<<dim3(24, 64), 128, 0, stream>>>(actb, inwbf, in_b, qkvP, 512, 512, 512, 0);
  flash_attn<<<dim3(256, 4), 256, 0, stream>>>(qkvP, Opart, Lpart);
  flash_combine<<<(NN * CC) / 256, 256, 0, stream>>>(Opart, Lpart, Ao);
  gemm_t<0, true><<<dim3(8, 64, 2), 128, 0, stream>>>(Ao, outwbf, out_b, proj, 256, 512, 512, 512);
  resid_ln<2><<<NN, 256, 0, stream>>>(h_f32, proj, ln2g, ln2b, x2_f32, actb);

  // --- FFN ---
  gemm_t<2, false><<<dim3(32, 64), 128, 0, stream>>>(actb, w1bf, b1, ffn1, 512, 512, 512, 2048);
  gemm_t<0, true><<<dim3(8, 64, 4), 128, 0, stream>>>(ffn1, w2bf, b2, proj, 512, 2048, 2048, 512);
  resid_ln<4><<<NN, 256, 0, stream>>>(x2_f32, proj, ln3g, ln3b, (float*)d_out, nullptr);
}

// Round 14
// 314.303 us; speedup vs baseline: 1.0686x; 1.0136x over previous
//
#include <hip/hip_runtime.h>
#include <math.h>

#define NN 4096
#define CC 512
#define EE 131072
#define NEDGE (EE + NN)
#define HH 8
#define DCO 64
#define NC2 2097152L   // NN*CC

typedef __attribute__((ext_vector_type(8))) short bfrag;
typedef __attribute__((ext_vector_type(4))) float f32x4;
typedef __attribute__((ext_vector_type(4))) int i32x4;

__device__ __forceinline__ float bf2f(unsigned short u) {
  union { float f; unsigned int i; } x; x.i = ((unsigned int)u) << 16; return x.f;
}
__device__ __forceinline__ unsigned short f2bf(float f) {
  union { float f; unsigned int i; } x; x.f = f;
  unsigned int r = x.i + 0x7FFFu + ((x.i >> 16) & 1u);
  return (unsigned short)(r >> 16);
}
__device__ __forceinline__ unsigned short f2bf_trunc(float f) {
  union { float f; unsigned int i; } x; x.f = f;
  return (unsigned short)(x.i >> 16);
}

__device__ __forceinline__ void gld16(const unsigned short* g, unsigned short* l) {
  __builtin_amdgcn_global_load_lds(
      (__attribute__((address_space(1))) unsigned int*)g,
      (__attribute__((address_space(3))) unsigned int*)l, 16, 0, 0);
}

// Q scale: (1/8) * log2(e)  -> scores in log2 domain, softmax = exp2
#define QSC 0.18033688011112042f

// ---------------- f32 -> bf16 bulk conversion + init fusion ----------------
#define CX  2097152L
#define CWL (CX + 262144L)
#define CWR (CWL + 262144L)
#define CIW (CWR + 786432L)
#define COW (CIW + 262144L)
#define CW1 (COW + 1048576L)
#define CW2 (CW1 + 1048576L)   // 5767168 = 5632 * 1024

__global__ void cvt_all(const float* __restrict__ x, const float* __restrict__ wl,
                        const float* __restrict__ wr, const float* __restrict__ iw,
                        const float* __restrict__ ow, const float* __restrict__ w1,
                        const float* __restrict__ w2, unsigned short* __restrict__ dst,
                        int* __restrict__ cntcur, const float* __restrict__ bl,
                        const float* __restrict__ br, float* __restrict__ biasc) {
  if (blockIdx.x >= 5632) {
    int t = threadIdx.x;
    if (blockIdx.x == 5632) {
      for (int k = t; k < 8192; k += 256) cntcur[k] = 0;
    } else {
      for (int k = t; k < 512; k += 256) {
        biasc[k] = bl[k];
        biasc[512 + k] = br[k];
      }
    }
    return;
  }
  long i = ((long)blockIdx.x * 256 + threadIdx.x) * 4;
  const float* s; long o;
  if (i < CX)       { s = x;  o = i; }
  else if (i < CWL) { s = wl; o = i - CX; }
  else if (i < CWR) { s = wr; o = i - CWL; }
  else if (i < CIW) { s = iw; o = i - CWR; }
  else if (i < COW) { s = ow; o = i - CIW; }
  else if (i < CW1) { s = w1; o = i - COW; }
  else              { s = w2; o = i - CW1; }
  f32x4 v = *(const f32x4*)(s + o);
  union { unsigned long long q; unsigned short u[4]; } t;
#pragma unroll
  for (int j = 0; j < 4; j++) t.u[j] = f2bf(v[j]);
  *(unsigned long long*)(dst + i) = t.q;
}

// ---------------- 128xTN bf16 GEMM: dbuf + counted vmcnt + RAW barriers ----
// Best-measured GEMM structure (R9, 310.8us total). __syncthreads compiles to
// "s_waitcnt vmcnt(0) lgkmcnt(0); s_barrier"; here: stage tile t+1 into the
// alternate buffer, wait vmcnt(N) = only tile t's loads (t+1's stay in
// flight), RAW s_barrier (no auto-drain). Deeper pipelines / other tiles /
// barrier removal all measured worse (R10-R12).
// OMODE: 0 f32 out (+split-K partial), 1 bf16 out, 2 bf16+GELU, 3 QKV scatter
template<int OMODE, int TN, bool SPLIT>
__global__ __launch_bounds__(256) void gemm_t(
    const unsigned short* __restrict__ A, const unsigned short* __restrict__ B,
    const float* __restrict__ bias, void* __restrict__ C,
    int K, int lda, int ldb, int ldc)
{
  __shared__ unsigned short As[2 * 4096];
  __shared__ unsigned short Bs[2 * TN * 32];
  constexpr int MI = (TN == 128) ? 4 : 2;
  constexpr int BS = TN * 32;
  const int tid = threadIdx.x;
  const int wave = tid >> 6, lane = tid & 63;
  const int ml = lane & 15, kq = lane >> 4;
  const int wm = (TN == 128) ? ((wave >> 1) << 6) : (wave << 5);
  const int wn = (TN == 128) ? ((wave & 1) << 6) : 0;
  const int bm = blockIdx.y << 7, bn = blockIdx.x * TN;
  const int srow = tid >> 2, scol = (tid & 3) << 3;
  if (SPLIT) { A += (long)blockIdx.z * K; B += (long)blockIdx.z * K; }
  const float* biasp = (!SPLIT || blockIdx.z == 0) ? bias : nullptr;
  const unsigned short* Ag = A + (long)(bm + srow) * lda + scol;
  const unsigned short* Bg = B + (long)(bn + srow) * ldb + scol;
  const long astep = (long)64 * lda, bstep = (long)64 * ldb;
  f32x4 acc[MI][4];
#pragma unroll
  for (int mi = 0; mi < MI; mi++)
#pragma unroll
    for (int ni = 0; ni < 4; ni++) acc[mi][ni] = (f32x4){0.f, 0.f, 0.f, 0.f};
  // prologue: stage tile 0 into buffer 0
  gld16(Ag, As + tid * 8);
  gld16(Ag + astep, As + 2048 + tid * 8);
  gld16(Bg, Bs + tid * 8);
  if (TN == 128) gld16(Bg + bstep, Bs + 2048 + tid * 8);
  Ag += 32; Bg += 32;
  const int nt = K >> 5;
  for (int t = 0; t < nt; t++) {
    const int cur = t & 1, nxt = cur ^ 1;
    if (t + 1 < nt) {
      gld16(Ag, As + nxt * 4096 + tid * 8);
      gld16(Ag + astep, As + nxt * 4096 + 2048 + tid * 8);
      gld16(Bg, Bs + nxt * BS + tid * 8);
      if (TN == 128) gld16(Bg + bstep, Bs + nxt * BS + 2048 + tid * 8);
      Ag += 32; Bg += 32;
      // wait only for tile t's loads; tile t+1's (just issued) stay in flight
      if (TN == 128) asm volatile("s_waitcnt vmcnt(4)" ::: "memory");
      else           asm volatile("s_waitcnt vmcnt(3)" ::: "memory");
    } else {
      asm volatile("s_waitcnt vmcnt(0)" ::: "memory");
    }
    __builtin_amdgcn_s_barrier();   // raw: no vmcnt(0) drain
    const unsigned short* Ab = As + cur * 4096;
    const unsigned short* Bb = Bs + cur * BS;
    bfrag af[MI], bf[4];
#pragma unroll
    for (int mi = 0; mi < MI; mi++)
      af[mi] = *(const bfrag*)&Ab[(wm + (mi << 4) + ml) * 32 + (kq << 3)];
#pragma unroll
    for (int ni = 0; ni < 4; ni++)
      bf[ni] = *(const bfrag*)&Bb[(wn + (ni << 4) + ml) * 32 + (kq << 3)];
#pragma unroll
    for (int mi = 0; mi < MI; mi++)
#pragma unroll
      for (int ni = 0; ni < 4; ni++)
        acc[mi][ni] = __builtin_amdgcn_mfma_f32_16x16x32_bf16(af[mi], bf[ni], acc[mi][ni], 0, 0, 0);
    __builtin_amdgcn_s_barrier();   // readers done before buf[cur] overwrite
  }
#pragma unroll
  for (int ni = 0; ni < 4; ni++) {
    int col = bn + wn + (ni << 4) + ml;
    float bb = biasp ? biasp[col] : 0.f;
#pragma unroll
    for (int mi = 0; mi < MI; mi++) {
      int row0 = bm + wm + (mi << 4) + (kq << 2);
#pragma unroll
      for (int r = 0; r < 4; r++) {
        float v = acc[mi][ni][r] + bb;
        int row = row0 + r;
        if (OMODE == 3) {
          unsigned short* q = (unsigned short*)C;
          if (col < 512) {
            int h = col >> 6, d = col & 63;
            q[(long)h * (NN * DCO) + (long)row * DCO + d] = f2bf(v * QSC);
          } else if (col < 1024) {
            int c2 = col - 512, h = c2 >> 6, d = c2 & 63;
            q[NC2 + (long)h * (NN * DCO) + (long)row * DCO + d] = f2bf(v);
          } else {
            int c2 = col - 1024, h = c2 >> 6, d = c2 & 63;
            q[2 * NC2 + (long)h * (DCO * NN) + (long)d * NN + row] = f2bf(v);
          }
        } else if (OMODE == 0) {
          long off = (SPLIT ? (long)blockIdx.z * NC2 : 0) + (long)row * ldc + col;
          ((float*)C)[off] = v;
        } else {
          if (OMODE == 2) v = 0.5f * v * (1.f + erff(v * 0.70710678118f));
          ((unsigned short*)C)[(long)row * ldc + col] = f2bf(v);
        }
      }
    }
  }
}

// ---------------- CSR build ----------------
__global__ void count_k(const int* __restrict__ ei, int* __restrict__ cnt) {
  int e = blockIdx.x * 256 + threadIdx.x;
  if (e >= NEDGE) return;
  int d = (e < EE) ? ei[EE + e] : (e - EE);
  atomicAdd(&cnt[d], 1);
}

__global__ void scan_k(const int* __restrict__ cnt, int* __restrict__ rowptr) {
  __shared__ int s[1024];
  int t = threadIdx.x;
  int b = t * 4;
  int c0 = cnt[b], c1 = cnt[b + 1], c2 = cnt[b + 2], c3 = cnt[b + 3];
  int sum = c0 + c1 + c2 + c3;
  s[t] = sum;
  __syncthreads();
  for (int o = 1; o < 1024; o <<= 1) {
    int v = (t >= o) ? s[t - o] : 0;
    __syncthreads();
    s[t] += v;
    __syncthreads();
  }
  int ex = s[t] - sum;
  rowptr[b] = ex; rowptr[b + 1] = ex + c0;
  rowptr[b + 2] = ex + c0 + c1; rowptr[b + 3] = ex + c0 + c1 + c2;
  if (t == 1023) rowptr[4096] = ex + sum;
}

__global__ void scatter_k(const int* __restrict__ ei, const int* __restrict__ rowptr,
                          int* __restrict__ cur, int* __restrict__ order) {
  int e = blockIdx.x * 256 + threadIdx.x;
  if (e >= NEDGE) return;
  int d = (e < EE) ? ei[EE + e] : (e - EE);
  int p = atomicAdd(&cur[d], 1);
  order[rowptr[d] + p] = e;
}

// ---------------- GATv2 fused: alpha + aggregate + residual + LayerNorm ----
__global__ __launch_bounds__(256) void gat_fused(
    const unsigned short* __restrict__ xlr, const float* __restrict__ x,
    const int* __restrict__ order, const int* __restrict__ rowptr,
    const int* __restrict__ ei, const float* __restrict__ att,
    const float* __restrict__ gbias,
    const float* __restrict__ g, const float* __restrict__ be,
    float* __restrict__ of, unsigned short* __restrict__ ob)
{
  __shared__ float part[4][512];
  __shared__ float sw[4][8];
  __shared__ float sinv[8];
  __shared__ float shl[8];
  int n = blockIdx.x, t = threadIdx.x;
  int beg = rowptr[n], deg = rowptr[n + 1] - beg;
  int wave = t >> 6, lane = t & 63;
  int ch = lane << 3;
  union U8 { i32x4 v; unsigned short u[8]; };
  // dst-side features: loaded once per node
  U8 XL; XL.v = *(const i32x4*)(xlr + (long)n * 1024 + ch);
  float xl[8];
#pragma unroll
  for (int j = 0; j < 8; j++) xl[j] = bf2f(XL.u[j]);
  f32x4 t0 = *(const f32x4*)(att + ch);
  f32x4 t1 = *(const f32x4*)(att + ch + 4);
  float acc[8];
#pragma unroll
  for (int j = 0; j < 8; j++) acc[j] = 0.f;
  float se = 0.f;
  int i = wave;
  U8 X;
  if (i < deg) {
    int e = order[beg + i];
    int sn = (e < EE) ? ei[e] : (e - EE);
    X.v = *(const i32x4*)(xlr + (long)sn * 1024 + 512 + ch);
  }
  while (i < deg) {
    U8 Xc = X;
    int inext = i + 4;
    if (inext < deg) {
      int e = order[beg + inext];
      int sn = (e < EE) ? ei[e] : (e - EE);
      X.v = *(const i32x4*)(xlr + (long)sn * 1024 + 512 + ch);
    }
    float xr[8];
    float p = 0.f;
#pragma unroll
    for (int j = 0; j < 8; j++) {
      xr[j] = bf2f(Xc.u[j]);
      float v = xl[j] + xr[j];
      v = (v > 0.f) ? v : 0.2f * v;
      float tv = (j < 4) ? t0[j] : t1[j - 4];
      p += tv * v;
    }
    // reduce over the 8 lanes of this head
    p += __shfl_xor(p, 1); p += __shfl_xor(p, 2); p += __shfl_xor(p, 4);
    float ew = __expf(p);
    se += ew;
#pragma unroll
    for (int j = 0; j < 8; j++) acc[j] += ew * xr[j];
    i = inext;
  }
  *(f32x4*)&part[wave][ch]     = (f32x4){acc[0], acc[1], acc[2], acc[3]};
  *(f32x4*)&part[wave][ch + 4] = (f32x4){acc[4], acc[5], acc[6], acc[7]};
  if ((lane & 7) == 0) sw[wave][lane >> 3] = se;
  __syncthreads();
  if (t < 8) sinv[t] = 1.f / (sw[0][t] + sw[1][t] + sw[2][t] + sw[3][t]);
  __syncthreads();
  long base = (long)n * CC;
  float v0, v1;
  {
    int c = t;
    float p4 = part[0][c] + part[1][c] + part[2][c] + part[3][c];
    v0 = x[base + c] + p4 * sinv[c >> 6] + gbias[c];
  }
  {
    int c = t + 256;
    float p4 = part[0][c] + part[1][c] + part[2][c] + part[3][c];
    v1 = x[base + c] + p4 * sinv[c >> 6] + gbias[c];
  }
  // LayerNorm over the 512-channel row
  float s = v0 + v1, ss = v0 * v0 + v1 * v1;
  for (int o = 32; o > 0; o >>= 1) { s += __shfl_down(s, o); ss += __shfl_down(ss, o); }
  if (lane == 0) { shl[wave] = s; shl[4 + wave] = ss; }
  __syncthreads();
  float S = shl[0] + shl[1] + shl[2] + shl[3];
  float SS = shl[4] + shl[5] + shl[6] + shl[7];
  float mean = S * (1.f / 512.f);
  float var = SS * (1.f / 512.f) - mean * mean;
  float rs = rsqrtf(var + 1e-5f);
  float y0 = (v0 - mean) * rs * g[t] + be[t];
  float y1 = (v1 - mean) * rs * g[t + 256] + be[t + 256];
  of[base + t] = y0; of[base + t + 256] = y1;
  ob[base + t] = f2bf(y0); ob[base + t + 256] = f2bf(y1);
}

// ---------------- residual + LayerNorm (NS partials summed for b) ----------
template<int NS>
__global__ __launch_bounds__(256) void resid_ln(
    const float* __restrict__ a, const float* __restrict__ b,
    const float* __restrict__ g, const float* __restrict__ be,
    float* __restrict__ of, unsigned short* __restrict__ ob)
{
  __shared__ float sh[8];
  int row = blockIdx.x, t = threadIdx.x;
  long base = (long)row * CC;
  float b0 = 0.f, b1 = 0.f;
#pragma unroll
  for (int s = 0; s < NS; s++) {
    b0 += b[(long)s * NC2 + base + t];
    b1 += b[(long)s * NC2 + base + t + 256];
  }
  float v0 = a[base + t] + b0;
  float v1 = a[base + t + 256] + b1;
  float s = v0 + v1, ss = v0 * v0 + v1 * v1;
  for (int o = 32; o > 0; o >>= 1) { s += __shfl_down(s, o); ss += __shfl_down(ss, o); }
  int wave = t >> 6, lane = t & 63;
  if (lane == 0) { sh[wave] = s; sh[4 + wave] = ss; }
  __syncthreads();
  float S = sh[0] + sh[1] + sh[2] + sh[3];
  float SS = sh[4] + sh[5] + sh[6] + sh[7];
  float mean = S * (1.f / 512.f);
  float var = SS * (1.f / 512.f) - mean * mean;
  float rs = rsqrtf(var + 1e-5f);
  float y0 = (v0 - mean) * rs * g[t] + be[t];
  float y1 = (v1 - mean) * rs * g[t + 256] + be[t + 256];
  if (of) { of[base + t] = y0; of[base + t + 256] = y1; }
  if (ob) { ob[base + t] = f2bf(y0); ob[base + t + 256] = f2bf(y1); }
}

// ---------------- flash attention: LDS-staged K/V, split-K x4, bf16 partials
// Swapped QK^T, b64 P-store, ones-MFMA row-sum, setprio around MFMA clusters.
// P-conversion: raw v_exp_f32 + v_cvt_pk_bf16_f32 in one asm block.
__global__ __launch_bounds__(256, 4) void flash_attn(
    const unsigned short* __restrict__ qkvP, unsigned short* __restrict__ Op,
    float* __restrict__ Lp)
{
  __shared__ unsigned short QP[128 * 72];
  __shared__ unsigned short Ks[64 * 72];
  __shared__ unsigned short Vs[64 * 72];
  const int tid = threadIdx.x;
  const int wave = tid >> 6, lane = tid & 63;
  const int ml = lane & 15, kq = lane >> 4;
  const int h = blockIdx.x & 7, qt = blockIdx.x >> 3;
  const int sp = blockIdx.y;
  const int n0 = qt << 7;
  const unsigned short* Qh = qkvP + (long)h * (NN * DCO);
  const unsigned short* Kh = qkvP + NC2 + (long)h * (NN * DCO);
  const unsigned short* Vh = qkvP + 2 * NC2 + (long)h * (DCO * NN);
  {
    int r = tid >> 1, c = (tid & 1) << 5;
    const unsigned short* src = Qh + (long)(n0 + r) * DCO + c;
    unsigned short* d = &QP[r * 72 + c];
    *(i32x4*)d        = *(const i32x4*)src;
    *(i32x4*)(d + 8)  = *(const i32x4*)(src + 8);
    *(i32x4*)(d + 16) = *(const i32x4*)(src + 16);
    *(i32x4*)(d + 24) = *(const i32x4*)(src + 24);
  }
  __syncthreads();
  bfrag aq[2][2];
#pragma unroll
  for (int s = 0; s < 2; s++)
#pragma unroll
    for (int kh = 0; kh < 2; kh++)
      aq[s][kh] = *(const bfrag*)&QP[(wave * 32 + s * 16 + ml) * 72 + kh * 32 + (kq << 3)];
  bfrag ones;
#pragma unroll
  for (int j = 0; j < 8; j++) ones[j] = (short)0x3F80;
  f32x4 Oa[2][4];
  f32x4 Lc[2];
#pragma unroll
  for (int s = 0; s < 2; s++) {
    Lc[s] = (f32x4){0.f, 0.f, 0.f, 0.f};
#pragma unroll
    for (int dg = 0; dg < 4; dg++) Oa[s][dg] = (f32x4){0.f, 0.f, 0.f, 0.f};
  }
  const int r_ = tid >> 2, c_ = (tid & 3) << 4;
  const int j0 = sp << 4;
  i32x4 ka, kb, va, vb;
  {
    int k0 = j0 << 6;
    ka = *(const i32x4*)(Kh + (long)(k0 + r_) * DCO + c_);
    kb = *(const i32x4*)(Kh + (long)(k0 + r_) * DCO + c_ + 8);
    va = *(const i32x4*)(Vh + (long)r_ * NN + k0 + c_);
    vb = *(const i32x4*)(Vh + (long)r_ * NN + k0 + c_ + 8);
  }
  for (int jj = 0; jj < 16; jj++) {
    if (jj) __syncthreads();
    *(i32x4*)&Ks[r_ * 72 + c_] = ka; *(i32x4*)&Ks[r_ * 72 + c_ + 8] = kb;
    *(i32x4*)&Vs[r_ * 72 + c_] = va; *(i32x4*)&Vs[r_ * 72 + c_ + 8] = vb;
    __syncthreads();
    if (jj < 15) {
      int k0 = (j0 + jj + 1) << 6;
      ka = *(const i32x4*)(Kh + (long)(k0 + r_) * DCO + c_);
      kb = *(const i32x4*)(Kh + (long)(k0 + r_) * DCO + c_ + 8);
      va = *(const i32x4*)(Vh + (long)r_ * NN + k0 + c_);
      vb = *(const i32x4*)(Vh + (long)r_ * NN + k0 + c_ + 8);
    }
    // S^T = K * Q^T : rows kv, cols q
    f32x4 sc[2][4];
#pragma unroll
    for (int s = 0; s < 2; s++)
#pragma unroll
      for (int c = 0; c < 4; c++) sc[s][c] = (f32x4){0.f, 0.f, 0.f, 0.f};
    __builtin_amdgcn_s_setprio(1);
#pragma unroll
    for (int c = 0; c < 4; c++) {
      bfrag bk0 = *(const bfrag*)&Ks[(c * 16 + ml) * 72 + (kq << 3)];
      bfrag bk1 = *(const bfrag*)&Ks[(c * 16 + ml) * 72 + 32 + (kq << 3)];
#pragma unroll
      for (int s = 0; s < 2; s++) {
        sc[s][c] = __builtin_amdgcn_mfma_f32_16x16x32_bf16(bk0, aq[s][0], sc[s][c], 0, 0, 0);
        sc[s][c] = __builtin_amdgcn_mfma_f32_16x16x32_bf16(bk1, aq[s][1], sc[s][c], 0, 0, 0);
      }
    }
    __builtin_amdgcn_s_setprio(0);
    // raw exp2 + pack to bf16 in one asm block; store P[q][kv] as b64
#pragma unroll
    for (int s = 0; s < 2; s++) {
#pragma unroll
      for (int c = 0; c < 4; c++) {
        unsigned int w0, w1;
        float e0, e1, e2, e3;
        asm("v_exp_f32 %2, %6\n\t"
            "v_exp_f32 %3, %7\n\t"
            "v_exp_f32 %4, %8\n\t"
            "v_exp_f32 %5, %9\n\t"
            "v_cvt_pk_bf16_f32 %0, %2, %3\n\t"
            "v_cvt_pk_bf16_f32 %1, %4, %5"
            : "=v"(w0), "=v"(w1), "=&v"(e0), "=&v"(e1), "=&v"(e2), "=&v"(e3)
            : "v"(sc[s][c][0]), "v"(sc[s][c][1]), "v"(sc[s][c][2]), "v"(sc[s][c][3]));
        union { unsigned long long q; unsigned int w[2]; } u;
        u.w[0] = w0; u.w[1] = w1;
        *(unsigned long long*)&QP[(wave * 32 + s * 16 + ml) * 72 + c * 16 + (kq << 2)] = u.q;
      }
    }
    bfrag ap[2][2];
#pragma unroll
    for (int s = 0; s < 2; s++)
#pragma unroll
      for (int kh = 0; kh < 2; kh++)
        ap[s][kh] = *(const bfrag*)&QP[(wave * 32 + s * 16 + ml) * 72 + kh * 32 + (kq << 3)];
    __builtin_amdgcn_s_setprio(1);
#pragma unroll
    for (int s = 0; s < 2; s++) {
      Lc[s] = __builtin_amdgcn_mfma_f32_16x16x32_bf16(ap[s][0], ones, Lc[s], 0, 0, 0);
      Lc[s] = __builtin_amdgcn_mfma_f32_16x16x32_bf16(ap[s][1], ones, Lc[s], 0, 0, 0);
    }
#pragma unroll
    for (int dg = 0; dg < 4; dg++) {
      bfrag bv0 = *(const bfrag*)&Vs[(dg * 16 + ml) * 72 + (kq << 3)];
      bfrag bv1 = *(const bfrag*)&Vs[(dg * 16 + ml) * 72 + 32 + (kq << 3)];
#pragma unroll
      for (int s = 0; s < 2; s++) {
        Oa[s][dg] = __builtin_amdgcn_mfma_f32_16x16x32_bf16(ap[s][0], bv0, Oa[s][dg], 0, 0, 0);
        Oa[s][dg] = __builtin_amdgcn_mfma_f32_16x16x32_bf16(ap[s][1], bv1, Oa[s][dg], 0, 0, 0);
      }
    }
    __builtin_amdgcn_s_setprio(0);
  }
  long obase = (long)sp * NC2;
#pragma unroll
  for (int s = 0; s < 2; s++)
#pragma unroll
    for (int dg = 0; dg < 4; dg++)
#pragma unroll
      for (int r = 0; r < 4; r++) {
        int row = wave * 32 + s * 16 + (kq << 2) + r;
        Op[obase + (long)(n0 + row) * CC + (h << 6) + (dg << 4) + ml] = f2bf(Oa[s][dg][r]);
      }
  if (ml == 0) {
#pragma unroll
    for (int s = 0; s < 2; s++)
#pragma unroll
      for (int r = 0; r < 4; r++) {
        int row = wave * 32 + s * 16 + (kq << 2) + r;
        Lp[(long)sp * (NN * HH) + (long)(n0 + row) * HH + h] = Lc[s][r];
      }
  }
}

__global__ void flash_combine(const unsigned short* __restrict__ Op,
                              const float* __restrict__ Lp,
                              unsigned short* __restrict__ Ao) {
  int idx = blockIdx.x * 256 + threadIdx.x;
  int n = idx >> 9, c = idx & 511, h = c >> 6;
  float l = 0.f, o = 0.f;
#pragma unroll
  for (int s = 0; s < 4; s++) {
    l += Lp[(long)s * (NN * HH) + (long)n * HH + h];
    o += bf2f(Op[(long)s * NC2 + idx]);
  }
  Ao[idx] = f2bf(o / l);
}

// ---------------- host orchestration ----------------
extern "C" void kernel_launch(void* const* d_in, const int* in_sizes, int n_in,
                              void* d_out, int out_size, void* d_ws, size_t ws_size,
                              hipStream_t stream) {
  typedef unsigned short u16;
  const float* x      = (const float*)d_in[0];
  const int*   ei     = (const int*)d_in[1];
  const float* wl     = (const float*)d_in[2];
  const float* bl     = (const float*)d_in[3];
  const float* wr     = (const float*)d_in[4];
  const float* br     = (const float*)d_in[5];
  const float* att    = (const float*)d_in[6];
  const float* gat_b  = (const float*)d_in[7];
  const float* in_w   = (const float*)d_in[8];
  const float* in_b   = (const float*)d_in[9];
  const float* out_w  = (const float*)d_in[10];
  const float* out_b  = (const float*)d_in[11];
  const float* ln1g   = (const float*)d_in[12];
  const float* ln1b   = (const float*)d_in[13];
  const float* ln2g   = (const float*)d_in[14];
  const float* ln2b   = (const float*)d_in[15];
  const float* ln3g   = (const float*)d_in[16];
  const float* ln3b   = (const float*)d_in[17];
  const float* w1     = (const float*)d_in[18];
  const float* b1     = (const float*)d_in[19];
  const float* w2     = (const float*)d_in[20];
  const float* b2     = (const float*)d_in[21];

  const size_t MB = 1u << 20;
  char* w = (char*)d_ws;
  float* h_f32   = (float*)(w + 0);                  // 8MB
  float* x2_f32  = (float*)(w + 8 * MB);             // 8MB
  int*   cnt     = (int*)(w + 16 * MB);              // 16KB, then cur 16KB
  int*   cur     = cnt + 4096;
  int*   rowptr  = (int*)(w + 16 * MB + 32 * 1024);
  int*   order   = (int*)(w + 16 * MB + 64 * 1024);  // 528KB
  u16*   cvt     = (u16*)(w + 17 * MB);              // 11.5MB
  u16*   xbf     = cvt;
  u16*   wlrbf   = cvt + CX;
  u16*   inwbf   = cvt + CWR;
  u16*   outwbf  = cvt + CIW;
  u16*   w1bf    = cvt + COW;
  u16*   w2bf    = cvt + CW1;
  // phase region [29MB..93MB)
  u16*   xlr_bf  = (u16*)(w + 29 * MB);              // GAT: 8MB
  u16*   Opart   = (u16*)(w + 29 * MB);              // flash: 16MB bf16 (GAT dead)
  float* proj    = (float*)(w + 29 * MB);            // post-combine: 32MB (4 partials)
  u16*   ffn1    = (u16*)(w + 61 * MB);              // 16MB -> 77MB
  u16*   qkvP    = (u16*)(w + 93 * MB);              // 12MB: Q | K | Vt
  float* biasc   = (float*)(w + 105 * MB);           // 4KB (pre-flash only)
  float* Lpart   = (float*)(w + 105 * MB);           // 512KB (flash phase)
  u16*   Ao      = (u16*)(w + 106 * MB);             // 4MB
  u16*   actb    = (u16*)(w + 110 * MB);             // 4MB; total 114MB

  // --- conversions + init + CSR ---
  cvt_all<<<5634, 256, 0, stream>>>(x, wl, wr, in_w, out_w, w1, w2, cvt,
                                    cnt, bl, br, biasc);
  count_k<<<(NEDGE + 255) / 256, 256, 0, stream>>>(ei, cnt);
  scan_k<<<1, 1024, 0, stream>>>(cnt, rowptr);
  scatter_k<<<(NEDGE + 255) / 256, 256, 0, stream>>>(ei, rowptr, cur, order);

  // --- GATv2 (alpha + aggregate + residual + LN1 fused into one kernel) ---
  gemm_t<1, 64, false><<<dim3(16, 32), 256, 0, stream>>>(xbf, wlrbf, biasc, xlr_bf, 512, 512, 512, 1024);
  gat_fused<<<NN, 256, 0, stream>>>(xlr_bf, x, order, rowptr, ei, att, gat_b,
                                    ln1g, ln1b, h_f32, actb);

  // --- MHA (QKV scatter fused into GEMM; staged flash, split-K x4) ---
  gemm_t<3, 64, false><<<dim3(24, 32), 256, 0, stream>>>(actb, inwbf, in_b, qkvP, 512, 512, 512, 0);
  flash_attn<<<dim3(256, 4), 256, 0, stream>>>(qkvP, Opart, Lpart);
  flash_combine<<<(NN * CC) / 256, 256, 0, stream>>>(Opart, Lpart, Ao);
  gemm_t<0, 64, true><<<dim3(8, 32, 2), 256, 0, stream>>>(Ao, outwbf, out_b, proj, 256, 512, 512, 512);
  resid_ln<2><<<NN, 256, 0, stream>>>(h_f32, proj, ln2g, ln2b, x2_f32, actb);

  // --- FFN (TN=64 tiles: 1024 blocks each -> 4 blocks/CU) ---
  gemm_t<2, 64, false><<<dim3(32, 32), 256, 0, stream>>>(actb, w1bf, b1, ffn1, 512, 512, 512, 2048);
  gemm_t<0, 64, true><<<dim3(8, 32, 4), 256, 0, stream>>>(ffn1, w2bf, b2, proj, 512, 2048, 2048, 512);
  resid_ln<4><<<NN, 256, 0, stream>>>(x2_f32, proj, ln3g, ln3b, (float*)d_out, nullptr);
}

// Round 15
// 309.218 us; speedup vs baseline: 1.0862x; 1.0164x over previous
//
#include <hip/hip_runtime.h>
#include <math.h>

#define NN 4096
#define CC 512
#define EE 131072
#define NEDGE (EE + NN)
#define HH 8
#define DCO 64
#define NC2 2097152L   // NN*CC

typedef __attribute__((ext_vector_type(8))) short bfrag;
typedef __attribute__((ext_vector_type(4))) float f32x4;
typedef __attribute__((ext_vector_type(4))) int i32x4;

__device__ __forceinline__ float bf2f(unsigned short u) {
  union { float f; unsigned int i; } x; x.i = ((unsigned int)u) << 16; return x.f;
}
__device__ __forceinline__ unsigned short f2bf(float f) {
  union { float f; unsigned int i; } x; x.f = f;
  unsigned int r = x.i + 0x7FFFu + ((x.i >> 16) & 1u);
  return (unsigned short)(r >> 16);
}
__device__ __forceinline__ unsigned short f2bf_trunc(float f) {
  union { float f; unsigned int i; } x; x.f = f;
  return (unsigned short)(x.i >> 16);
}

__device__ __forceinline__ void gld16(const unsigned short* g, unsigned short* l) {
  __builtin_amdgcn_global_load_lds(
      (__attribute__((address_space(1))) unsigned int*)g,
      (__attribute__((address_space(3))) unsigned int*)l, 16, 0, 0);
}

// Q scale: (1/8) * log2(e)  -> scores in log2 domain, softmax = exp2
#define QSC 0.18033688011112042f

// ---------------- f32 -> bf16 bulk conversion + init fusion ----------------
#define CX  2097152L
#define CWL (CX + 262144L)
#define CWR (CWL + 262144L)
#define CIW (CWR + 786432L)
#define COW (CIW + 262144L)
#define CW1 (COW + 1048576L)
#define CW2 (CW1 + 1048576L)   // 5767168 = 5632 * 1024

__global__ void cvt_all(const float* __restrict__ x, const float* __restrict__ wl,
                        const float* __restrict__ wr, const float* __restrict__ iw,
                        const float* __restrict__ ow, const float* __restrict__ w1,
                        const float* __restrict__ w2, unsigned short* __restrict__ dst,
                        int* __restrict__ cntcur, const float* __restrict__ bl,
                        const float* __restrict__ br, float* __restrict__ biasc) {
  if (blockIdx.x >= 5632) {
    int t = threadIdx.x;
    if (blockIdx.x == 5632) {
      for (int k = t; k < 8192; k += 256) cntcur[k] = 0;
    } else {
      for (int k = t; k < 512; k += 256) {
        biasc[k] = bl[k];
        biasc[512 + k] = br[k];
      }
    }
    return;
  }
  long i = ((long)blockIdx.x * 256 + threadIdx.x) * 4;
  const float* s; long o;
  if (i < CX)       { s = x;  o = i; }
  else if (i < CWL) { s = wl; o = i - CX; }
  else if (i < CWR) { s = wr; o = i - CWL; }
  else if (i < CIW) { s = iw; o = i - CWR; }
  else if (i < COW) { s = ow; o = i - CIW; }
  else if (i < CW1) { s = w1; o = i - COW; }
  else              { s = w2; o = i - CW1; }
  f32x4 v = *(const f32x4*)(s + o);
  union { unsigned long long q; unsigned short u[4]; } t;
#pragma unroll
  for (int j = 0; j < 4; j++) t.u[j] = f2bf(v[j]);
  *(unsigned long long*)(dst + i) = t.q;
}

// ---------------- 128xTN bf16 GEMM: R9 pipeline + XCD-aware block swizzle --
// R9 pipeline (best measured): dbuf + counted vmcnt + RAW barriers.
// NEW (T1): bijective XCD remap. Default dispatch round-robins linear IDs
// across 8 XCDs -> every XCD touches ALL A panels (4MB) + B (2MB) > 4MB L2
// (FFN1 FETCH 17.6MB vs 6MB compulsory = 3x HBM over-fetch). Remap gives
// XCD k a contiguous blockIdx.y range: per-XCD set = gridY/8 A-panels
// (512KB) + B (<=2MB) < L2. gridY=32 (div by 8) for all launches.
// OMODE: 0 f32 out (+split-K partial), 1 bf16 out, 2 bf16+GELU, 3 QKV scatter
template<int OMODE, int TN, bool SPLIT>
__global__ __launch_bounds__(256) void gemm_t(
    const unsigned short* __restrict__ A, const unsigned short* __restrict__ B,
    const float* __restrict__ bias, void* __restrict__ C,
    int K, int lda, int ldb, int ldc)
{
  __shared__ unsigned short As[2 * 4096];
  __shared__ unsigned short Bs[2 * TN * 32];
  constexpr int MI = (TN == 128) ? 4 : 2;
  constexpr int BS = TN * 32;
  const int tid = threadIdx.x;
  const int wave = tid >> 6, lane = tid & 63;
  const int ml = lane & 15, kq = lane >> 4;
  const int wm = (TN == 128) ? ((wave >> 1) << 6) : (wave << 5);
  const int wn = (TN == 128) ? ((wave & 1) << 6) : 0;
  // --- XCD-aware bijective remap (hw: linear id i -> XCD i%8) ---
  const int nwgx = gridDim.x;
  const int i_lin = blockIdx.y * nwgx + blockIdx.x;
  const int xcd = i_lin & 7;
  const int j = i_lin >> 3;
  const int rpx = gridDim.y >> 3;              // y-panels per XCD (gridY%8==0)
  const int by = xcd * rpx + j / nwgx;
  const int bx = j - (j / nwgx) * nwgx;
  const int bm = by << 7, bn = bx * TN;
  const int srow = tid >> 2, scol = (tid & 3) << 3;
  if (SPLIT) { A += (long)blockIdx.z * K; B += (long)blockIdx.z * K; }
  const float* biasp = (!SPLIT || blockIdx.z == 0) ? bias : nullptr;
  const unsigned short* Ag = A + (long)(bm + srow) * lda + scol;
  const unsigned short* Bg = B + (long)(bn + srow) * ldb + scol;
  const long astep = (long)64 * lda, bstep = (long)64 * ldb;
  f32x4 acc[MI][4];
#pragma unroll
  for (int mi = 0; mi < MI; mi++)
#pragma unroll
    for (int ni = 0; ni < 4; ni++) acc[mi][ni] = (f32x4){0.f, 0.f, 0.f, 0.f};
  // prologue: stage tile 0 into buffer 0
  gld16(Ag, As + tid * 8);
  gld16(Ag + astep, As + 2048 + tid * 8);
  gld16(Bg, Bs + tid * 8);
  if (TN == 128) gld16(Bg + bstep, Bs + 2048 + tid * 8);
  Ag += 32; Bg += 32;
  const int nt = K >> 5;
  for (int t = 0; t < nt; t++) {
    const int cur = t & 1, nxt = cur ^ 1;
    if (t + 1 < nt) {
      gld16(Ag, As + nxt * 4096 + tid * 8);
      gld16(Ag + astep, As + nxt * 4096 + 2048 + tid * 8);
      gld16(Bg, Bs + nxt * BS + tid * 8);
      if (TN == 128) gld16(Bg + bstep, Bs + nxt * BS + 2048 + tid * 8);
      Ag += 32; Bg += 32;
      // wait only for tile t's loads; tile t+1's (just issued) stay in flight
      if (TN == 128) asm volatile("s_waitcnt vmcnt(4)" ::: "memory");
      else           asm volatile("s_waitcnt vmcnt(3)" ::: "memory");
    } else {
      asm volatile("s_waitcnt vmcnt(0)" ::: "memory");
    }
    __builtin_amdgcn_s_barrier();   // raw: no vmcnt(0) drain
    const unsigned short* Ab = As + cur * 4096;
    const unsigned short* Bb = Bs + cur * BS;
    bfrag af[MI], bf[4];
#pragma unroll
    for (int mi = 0; mi < MI; mi++)
      af[mi] = *(const bfrag*)&Ab[(wm + (mi << 4) + ml) * 32 + (kq << 3)];
#pragma unroll
    for (int ni = 0; ni < 4; ni++)
      bf[ni] = *(const bfrag*)&Bb[(wn + (ni << 4) + ml) * 32 + (kq << 3)];
#pragma unroll
    for (int mi = 0; mi < MI; mi++)
#pragma unroll
      for (int ni = 0; ni < 4; ni++)
        acc[mi][ni] = __builtin_amdgcn_mfma_f32_16x16x32_bf16(af[mi], bf[ni], acc[mi][ni], 0, 0, 0);
    __builtin_amdgcn_s_barrier();   // readers done before buf[cur] overwrite
  }
#pragma unroll
  for (int ni = 0; ni < 4; ni++) {
    int col = bn + wn + (ni << 4) + ml;
    float bb = biasp ? biasp[col] : 0.f;
#pragma unroll
    for (int mi = 0; mi < MI; mi++) {
      int row0 = bm + wm + (mi << 4) + (kq << 2);
#pragma unroll
      for (int r = 0; r < 4; r++) {
        float v = acc[mi][ni][r] + bb;
        int row = row0 + r;
        if (OMODE == 3) {
          unsigned short* q = (unsigned short*)C;
          if (col < 512) {
            int h = col >> 6, d = col & 63;
            q[(long)h * (NN * DCO) + (long)row * DCO + d] = f2bf(v * QSC);
          } else if (col < 1024) {
            int c2 = col - 512, h = c2 >> 6, d = c2 & 63;
            q[NC2 + (long)h * (NN * DCO) + (long)row * DCO + d] = f2bf(v);
          } else {
            int c2 = col - 1024, h = c2 >> 6, d = c2 & 63;
            q[2 * NC2 + (long)h * (DCO * NN) + (long)d * NN + row] = f2bf(v);
          }
        } else if (OMODE == 0) {
          long off = (SPLIT ? (long)blockIdx.z * NC2 : 0) + (long)row * ldc + col;
          ((float*)C)[off] = v;
        } else {
          if (OMODE == 2) v = 0.5f * v * (1.f + erff(v * 0.70710678118f));
          ((unsigned short*)C)[(long)row * ldc + col] = f2bf(v);
        }
      }
    }
  }
}

// ---------------- CSR build ----------------
__global__ void count_k(const int* __restrict__ ei, int* __restrict__ cnt) {
  int e = blockIdx.x * 256 + threadIdx.x;
  if (e >= NEDGE) return;
  int d = (e < EE) ? ei[EE + e] : (e - EE);
  atomicAdd(&cnt[d], 1);
}

__global__ void scan_k(const int* __restrict__ cnt, int* __restrict__ rowptr) {
  __shared__ int s[1024];
  int t = threadIdx.x;
  int b = t * 4;
  int c0 = cnt[b], c1 = cnt[b + 1], c2 = cnt[b + 2], c3 = cnt[b + 3];
  int sum = c0 + c1 + c2 + c3;
  s[t] = sum;
  __syncthreads();
  for (int o = 1; o < 1024; o <<= 1) {
    int v = (t >= o) ? s[t - o] : 0;
    __syncthreads();
    s[t] += v;
    __syncthreads();
  }
  int ex = s[t] - sum;
  rowptr[b] = ex; rowptr[b + 1] = ex + c0;
  rowptr[b + 2] = ex + c0 + c1; rowptr[b + 3] = ex + c0 + c1 + c2;
  if (t == 1023) rowptr[4096] = ex + sum;
}

__global__ void scatter_k(const int* __restrict__ ei, const int* __restrict__ rowptr,
                          int* __restrict__ cur, int* __restrict__ order) {
  int e = blockIdx.x * 256 + threadIdx.x;
  if (e >= NEDGE) return;
  int d = (e < EE) ? ei[EE + e] : (e - EE);
  int p = atomicAdd(&cur[d], 1);
  order[rowptr[d] + p] = e;
}

// ---------------- GATv2 fused: alpha + aggregate + residual + LayerNorm ----
__global__ __launch_bounds__(256) void gat_fused(
    const unsigned short* __restrict__ xlr, const float* __restrict__ x,
    const int* __restrict__ order, const int* __restrict__ rowptr,
    const int* __restrict__ ei, const float* __restrict__ att,
    const float* __restrict__ gbias,
    const float* __restrict__ g, const float* __restrict__ be,
    float* __restrict__ of, unsigned short* __restrict__ ob)
{
  __shared__ float part[4][512];
  __shared__ float sw[4][8];
  __shared__ float sinv[8];
  __shared__ float shl[8];
  int n = blockIdx.x, t = threadIdx.x;
  int beg = rowptr[n], deg = rowptr[n + 1] - beg;
  int wave = t >> 6, lane = t & 63;
  int ch = lane << 3;
  union U8 { i32x4 v; unsigned short u[8]; };
  // dst-side features: loaded once per node
  U8 XL; XL.v = *(const i32x4*)(xlr + (long)n * 1024 + ch);
  float xl[8];
#pragma unroll
  for (int j = 0; j < 8; j++) xl[j] = bf2f(XL.u[j]);
  f32x4 t0 = *(const f32x4*)(att + ch);
  f32x4 t1 = *(const f32x4*)(att + ch + 4);
  float acc[8];
#pragma unroll
  for (int j = 0; j < 8; j++) acc[j] = 0.f;
  float se = 0.f;
  int i = wave;
  U8 X;
  if (i < deg) {
    int e = order[beg + i];
    int sn = (e < EE) ? ei[e] : (e - EE);
    X.v = *(const i32x4*)(xlr + (long)sn * 1024 + 512 + ch);
  }
  while (i < deg) {
    U8 Xc = X;
    int inext = i + 4;
    if (inext < deg) {
      int e = order[beg + inext];
      int sn = (e < EE) ? ei[e] : (e - EE);
      X.v = *(const i32x4*)(xlr + (long)sn * 1024 + 512 + ch);
    }
    float xr[8];
    float p = 0.f;
#pragma unroll
    for (int j = 0; j < 8; j++) {
      xr[j] = bf2f(Xc.u[j]);
      float v = xl[j] + xr[j];
      v = (v > 0.f) ? v : 0.2f * v;
      float tv = (j < 4) ? t0[j] : t1[j - 4];
      p += tv * v;
    }
    // reduce over the 8 lanes of this head
    p += __shfl_xor(p, 1); p += __shfl_xor(p, 2); p += __shfl_xor(p, 4);
    float ew = __expf(p);
    se += ew;
#pragma unroll
    for (int j = 0; j < 8; j++) acc[j] += ew * xr[j];
    i = inext;
  }
  *(f32x4*)&part[wave][ch]     = (f32x4){acc[0], acc[1], acc[2], acc[3]};
  *(f32x4*)&part[wave][ch + 4] = (f32x4){acc[4], acc[5], acc[6], acc[7]};
  if ((lane & 7) == 0) sw[wave][lane >> 3] = se;
  __syncthreads();
  if (t < 8) sinv[t] = 1.f / (sw[0][t] + sw[1][t] + sw[2][t] + sw[3][t]);
  __syncthreads();
  long base = (long)n * CC;
  float v0, v1;
  {
    int c = t;
    float p4 = part[0][c] + part[1][c] + part[2][c] + part[3][c];
    v0 = x[base + c] + p4 * sinv[c >> 6] + gbias[c];
  }
  {
    int c = t + 256;
    float p4 = part[0][c] + part[1][c] + part[2][c] + part[3][c];
    v1 = x[base + c] + p4 * sinv[c >> 6] + gbias[c];
  }
  // LayerNorm over the 512-channel row
  float s = v0 + v1, ss = v0 * v0 + v1 * v1;
  for (int o = 32; o > 0; o >>= 1) { s += __shfl_down(s, o); ss += __shfl_down(ss, o); }
  if (lane == 0) { shl[wave] = s; shl[4 + wave] = ss; }
  __syncthreads();
  float S = shl[0] + shl[1] + shl[2] + shl[3];
  float SS = shl[4] + shl[5] + shl[6] + shl[7];
  float mean = S * (1.f / 512.f);
  float var = SS * (1.f / 512.f) - mean * mean;
  float rs = rsqrtf(var + 1e-5f);
  float y0 = (v0 - mean) * rs * g[t] + be[t];
  float y1 = (v1 - mean) * rs * g[t + 256] + be[t + 256];
  of[base + t] = y0; of[base + t + 256] = y1;
  ob[base + t] = f2bf(y0); ob[base + t + 256] = f2bf(y1);
}

// ---------------- residual + LayerNorm (NS partials summed for b) ----------
template<int NS>
__global__ __launch_bounds__(256) void resid_ln(
    const float* __restrict__ a, const float* __restrict__ b,
    const float* __restrict__ g, const float* __restrict__ be,
    float* __restrict__ of, unsigned short* __restrict__ ob)
{
  __shared__ float sh[8];
  int row = blockIdx.x, t = threadIdx.x;
  long base = (long)row * CC;
  float b0 = 0.f, b1 = 0.f;
#pragma unroll
  for (int s = 0; s < NS; s++) {
    b0 += b[(long)s * NC2 + base + t];
    b1 += b[(long)s * NC2 + base + t + 256];
  }
  float v0 = a[base + t] + b0;
  float v1 = a[base + t + 256] + b1;
  float s = v0 + v1, ss = v0 * v0 + v1 * v1;
  for (int o = 32; o > 0; o >>= 1) { s += __shfl_down(s, o); ss += __shfl_down(ss, o); }
  int wave = t >> 6, lane = t & 63;
  if (lane == 0) { sh[wave] = s; sh[4 + wave] = ss; }
  __syncthreads();
  float S = sh[0] + sh[1] + sh[2] + sh[3];
  float SS = sh[4] + sh[5] + sh[6] + sh[7];
  float mean = S * (1.f / 512.f);
  float var = SS * (1.f / 512.f) - mean * mean;
  float rs = rsqrtf(var + 1e-5f);
  float y0 = (v0 - mean) * rs * g[t] + be[t];
  float y1 = (v1 - mean) * rs * g[t + 256] + be[t + 256];
  if (of) { of[base + t] = y0; of[base + t + 256] = y1; }
  if (ob) { ob[base + t] = f2bf(y0); ob[base + t + 256] = f2bf(y1); }
}

// ---------------- flash attention: LDS-staged K/V, split-K x4, bf16 partials
// Swapped QK^T, b64 P-store, ones-MFMA row-sum, setprio around MFMA clusters.
// P-conversion: raw v_exp_f32 + v_cvt_pk_bf16_f32 in one asm block.
__global__ __launch_bounds__(256, 4) void flash_attn(
    const unsigned short* __restrict__ qkvP, unsigned short* __restrict__ Op,
    float* __restrict__ Lp)
{
  __shared__ unsigned short QP[128 * 72];
  __shared__ unsigned short Ks[64 * 72];
  __shared__ unsigned short Vs[64 * 72];
  const int tid = threadIdx.x;
  const int wave = tid >> 6, lane = tid & 63;
  const int ml = lane & 15, kq = lane >> 4;
  const int h = blockIdx.x & 7, qt = blockIdx.x >> 3;
  const int sp = blockIdx.y;
  const int n0 = qt << 7;
  const unsigned short* Qh = qkvP + (long)h * (NN * DCO);
  const unsigned short* Kh = qkvP + NC2 + (long)h * (NN * DCO);
  const unsigned short* Vh = qkvP + 2 * NC2 + (long)h * (DCO * NN);
  {
    int r = tid >> 1, c = (tid & 1) << 5;
    const unsigned short* src = Qh + (long)(n0 + r) * DCO + c;
    unsigned short* d = &QP[r * 72 + c];
    *(i32x4*)d        = *(const i32x4*)src;
    *(i32x4*)(d + 8)  = *(const i32x4*)(src + 8);
    *(i32x4*)(d + 16) = *(const i32x4*)(src + 16);
    *(i32x4*)(d + 24) = *(const i32x4*)(src + 24);
  }
  __syncthreads();
  bfrag aq[2][2];
#pragma unroll
  for (int s = 0; s < 2; s++)
#pragma unroll
    for (int kh = 0; kh < 2; kh++)
      aq[s][kh] = *(const bfrag*)&QP[(wave * 32 + s * 16 + ml) * 72 + kh * 32 + (kq << 3)];
  bfrag ones;
#pragma unroll
  for (int j = 0; j < 8; j++) ones[j] = (short)0x3F80;
  f32x4 Oa[2][4];
  f32x4 Lc[2];
#pragma unroll
  for (int s = 0; s < 2; s++) {
    Lc[s] = (f32x4){0.f, 0.f, 0.f, 0.f};
#pragma unroll
    for (int dg = 0; dg < 4; dg++) Oa[s][dg] = (f32x4){0.f, 0.f, 0.f, 0.f};
  }
  const int r_ = tid >> 2, c_ = (tid & 3) << 4;
  const int j0 = sp << 4;
  i32x4 ka, kb, va, vb;
  {
    int k0 = j0 << 6;
    ka = *(const i32x4*)(Kh + (long)(k0 + r_) * DCO + c_);
    kb = *(const i32x4*)(Kh + (long)(k0 + r_) * DCO + c_ + 8);
    va = *(const i32x4*)(Vh + (long)r_ * NN + k0 + c_);
    vb = *(const i32x4*)(Vh + (long)r_ * NN + k0 + c_ + 8);
  }
  for (int jj = 0; jj < 16; jj++) {
    if (jj) __syncthreads();
    *(i32x4*)&Ks[r_ * 72 + c_] = ka; *(i32x4*)&Ks[r_ * 72 + c_ + 8] = kb;
    *(i32x4*)&Vs[r_ * 72 + c_] = va; *(i32x4*)&Vs[r_ * 72 + c_ + 8] = vb;
    __syncthreads();
    if (jj < 15) {
      int k0 = (j0 + jj + 1) << 6;
      ka = *(const i32x4*)(Kh + (long)(k0 + r_) * DCO + c_);
      kb = *(const i32x4*)(Kh + (long)(k0 + r_) * DCO + c_ + 8);
      va = *(const i32x4*)(Vh + (long)r_ * NN + k0 + c_);
      vb = *(const i32x4*)(Vh + (long)r_ * NN + k0 + c_ + 8);
    }
    // S^T = K * Q^T : rows kv, cols q
    f32x4 sc[2][4];
#pragma unroll
    for (int s = 0; s < 2; s++)
#pragma unroll
      for (int c = 0; c < 4; c++) sc[s][c] = (f32x4){0.f, 0.f, 0.f, 0.f};
    __builtin_amdgcn_s_setprio(1);
#pragma unroll
    for (int c = 0; c < 4; c++) {
      bfrag bk0 = *(const bfrag*)&Ks[(c * 16 + ml) * 72 + (kq << 3)];
      bfrag bk1 = *(const bfrag*)&Ks[(c * 16 + ml) * 72 + 32 + (kq << 3)];
#pragma unroll
      for (int s = 0; s < 2; s++) {
        sc[s][c] = __builtin_amdgcn_mfma_f32_16x16x32_bf16(bk0, aq[s][0], sc[s][c], 0, 0, 0);
        sc[s][c] = __builtin_amdgcn_mfma_f32_16x16x32_bf16(bk1, aq[s][1], sc[s][c], 0, 0, 0);
      }
    }
    __builtin_amdgcn_s_setprio(0);
    // raw exp2 + pack to bf16 in one asm block; store P[q][kv] as b64
#pragma unroll
    for (int s = 0; s < 2; s++) {
#pragma unroll
      for (int c = 0; c < 4; c++) {
        unsigned int w0, w1;
        float e0, e1, e2, e3;
        asm("v_exp_f32 %2, %6\n\t"
            "v_exp_f32 %3, %7\n\t"
            "v_exp_f32 %4, %8\n\t"
            "v_exp_f32 %5, %9\n\t"
            "v_cvt_pk_bf16_f32 %0, %2, %3\n\t"
            "v_cvt_pk_bf16_f32 %1, %4, %5"
            : "=v"(w0), "=v"(w1), "=&v"(e0), "=&v"(e1), "=&v"(e2), "=&v"(e3)
            : "v"(sc[s][c][0]), "v"(sc[s][c][1]), "v"(sc[s][c][2]), "v"(sc[s][c][3]));
        union { unsigned long long q; unsigned int w[2]; } u;
        u.w[0] = w0; u.w[1] = w1;
        *(unsigned long long*)&QP[(wave * 32 + s * 16 + ml) * 72 + c * 16 + (kq << 2)] = u.q;
      }
    }
    bfrag ap[2][2];
#pragma unroll
    for (int s = 0; s < 2; s++)
#pragma unroll
      for (int kh = 0; kh < 2; kh++)
        ap[s][kh] = *(const bfrag*)&QP[(wave * 32 + s * 16 + ml) * 72 + kh * 32 + (kq << 3)];
    __builtin_amdgcn_s_setprio(1);
#pragma unroll
    for (int s = 0; s < 2; s++) {
      Lc[s] = __builtin_amdgcn_mfma_f32_16x16x32_bf16(ap[s][0], ones, Lc[s], 0, 0, 0);
      Lc[s] = __builtin_amdgcn_mfma_f32_16x16x32_bf16(ap[s][1], ones, Lc[s], 0, 0, 0);
    }
#pragma unroll
    for (int dg = 0; dg < 4; dg++) {
      bfrag bv0 = *(const bfrag*)&Vs[(dg * 16 + ml) * 72 + (kq << 3)];
      bfrag bv1 = *(const bfrag*)&Vs[(dg * 16 + ml) * 72 + 32 + (kq << 3)];
#pragma unroll
      for (int s = 0; s < 2; s++) {
        Oa[s][dg] = __builtin_amdgcn_mfma_f32_16x16x32_bf16(ap[s][0], bv0, Oa[s][dg], 0, 0, 0);
        Oa[s][dg] = __builtin_amdgcn_mfma_f32_16x16x32_bf16(ap[s][1], bv1, Oa[s][dg], 0, 0, 0);
      }
    }
    __builtin_amdgcn_s_setprio(0);
  }
  long obase = (long)sp * NC2;
#pragma unroll
  for (int s = 0; s < 2; s++)
#pragma unroll
    for (int dg = 0; dg < 4; dg++)
#pragma unroll
      for (int r = 0; r < 4; r++) {
        int row = wave * 32 + s * 16 + (kq << 2) + r;
        Op[obase + (long)(n0 + row) * CC + (h << 6) + (dg << 4) + ml] = f2bf(Oa[s][dg][r]);
      }
  if (ml == 0) {
#pragma unroll
    for (int s = 0; s < 2; s++)
#pragma unroll
      for (int r = 0; r < 4; r++) {
        int row = wave * 32 + s * 16 + (kq << 2) + r;
        Lp[(long)sp * (NN * HH) + (long)(n0 + row) * HH + h] = Lc[s][r];
      }
  }
}

__global__ void flash_combine(const unsigned short* __restrict__ Op,
                              const float* __restrict__ Lp,
                              unsigned short* __restrict__ Ao) {
  int idx = blockIdx.x * 256 + threadIdx.x;
  int n = idx >> 9, c = idx & 511, h = c >> 6;
  float l = 0.f, o = 0.f;
#pragma unroll
  for (int s = 0; s < 4; s++) {
    l += Lp[(long)s * (NN * HH) + (long)n * HH + h];
    o += bf2f(Op[(long)s * NC2 + idx]);
  }
  Ao[idx] = f2bf(o / l);
}

// ---------------- host orchestration ----------------
extern "C" void kernel_launch(void* const* d_in, const int* in_sizes, int n_in,
                              void* d_out, int out_size, void* d_ws, size_t ws_size,
                              hipStream_t stream) {
  typedef unsigned short u16;
  const float* x      = (const float*)d_in[0];
  const int*   ei     = (const int*)d_in[1];
  const float* wl     = (const float*)d_in[2];
  const float* bl     = (const float*)d_in[3];
  const float* wr     = (const float*)d_in[4];
  const float* br     = (const float*)d_in[5];
  const float* att    = (const float*)d_in[6];
  const float* gat_b  = (const float*)d_in[7];
  const float* in_w   = (const float*)d_in[8];
  const float* in_b   = (const float*)d_in[9];
  const float* out_w  = (const float*)d_in[10];
  const float* out_b  = (const float*)d_in[11];
  const float* ln1g   = (const float*)d_in[12];
  const float* ln1b   = (const float*)d_in[13];
  const float* ln2g   = (const float*)d_in[14];
  const float* ln2b   = (const float*)d_in[15];
  const float* ln3g   = (const float*)d_in[16];
  const float* ln3b   = (const float*)d_in[17];
  const float* w1     = (const float*)d_in[18];
  const float* b1     = (const float*)d_in[19];
  const float* w2     = (const float*)d_in[20];
  const float* b2     = (const float*)d_in[21];

  const size_t MB = 1u << 20;
  char* w = (char*)d_ws;
  float* h_f32   = (float*)(w + 0);                  // 8MB
  float* x2_f32  = (float*)(w + 8 * MB);             // 8MB
  int*   cnt     = (int*)(w + 16 * MB);              // 16KB, then cur 16KB
  int*   cur     = cnt + 4096;
  int*   rowptr  = (int*)(w + 16 * MB + 32 * 1024);
  int*   order   = (int*)(w + 16 * MB + 64 * 1024);  // 528KB
  u16*   cvt     = (u16*)(w + 17 * MB);              // 11.5MB
  u16*   xbf     = cvt;
  u16*   wlrbf   = cvt + CX;
  u16*   inwbf   = cvt + CWR;
  u16*   outwbf  = cvt + CIW;
  u16*   w1bf    = cvt + COW;
  u16*   w2bf    = cvt + CW1;
  // phase region [29MB..93MB)
  u16*   xlr_bf  = (u16*)(w + 29 * MB);              // GAT: 8MB
  u16*   Opart   = (u16*)(w + 29 * MB);              // flash: 16MB bf16 (GAT dead)
  float* proj    = (float*)(w + 29 * MB);            // post-combine: 32MB (4 partials)
  u16*   ffn1    = (u16*)(w + 61 * MB);              // 16MB -> 77MB
  u16*   qkvP    = (u16*)(w + 93 * MB);              // 12MB: Q | K | Vt
  float* biasc   = (float*)(w + 105 * MB);           // 4KB (pre-flash only)
  float* Lpart   = (float*)(w + 105 * MB);           // 512KB (flash phase)
  u16*   Ao      = (u16*)(w + 106 * MB);             // 4MB
  u16*   actb    = (u16*)(w + 110 * MB);             // 4MB; total 114MB

  // --- conversions + init + CSR ---
  cvt_all<<<5634, 256, 0, stream>>>(x, wl, wr, in_w, out_w, w1, w2, cvt,
                                    cnt, bl, br, biasc);
  count_k<<<(NEDGE + 255) / 256, 256, 0, stream>>>(ei, cnt);
  scan_k<<<1, 1024, 0, stream>>>(cnt, rowptr);
  scatter_k<<<(NEDGE + 255) / 256, 256, 0, stream>>>(ei, rowptr, cur, order);

  // --- GATv2 (alpha + aggregate + residual + LN1 fused into one kernel) ---
  gemm_t<1, 64, false><<<dim3(16, 32), 256, 0, stream>>>(xbf, wlrbf, biasc, xlr_bf, 512, 512, 512, 1024);
  gat_fused<<<NN, 256, 0, stream>>>(xlr_bf, x, order, rowptr, ei, att, gat_b,
                                    ln1g, ln1b, h_f32, actb);

  // --- MHA (QKV scatter fused into GEMM; staged flash, split-K x4) ---
  gemm_t<3, 64, false><<<dim3(24, 32), 256, 0, stream>>>(actb, inwbf, in_b, qkvP, 512, 512, 512, 0);
  flash_attn<<<dim3(256, 4), 256, 0, stream>>>(qkvP, Opart, Lpart);
  flash_combine<<<(NN * CC) / 256, 256, 0, stream>>>(Opart, Lpart, Ao);
  gemm_t<0, 64, true><<<dim3(8, 32, 2), 256, 0, stream>>>(Ao, outwbf, out_b, proj, 256, 512, 512, 512);
  resid_ln<2><<<NN, 256, 0, stream>>>(h_f32, proj, ln2g, ln2b, x2_f32, actb);

  // --- FFN (TN=64 tiles: 1024 blocks each -> 4 blocks/CU) ---
  gemm_t<2, 64, false><<<dim3(32, 32), 256, 0, stream>>>(actb, w1bf, b1, ffn1, 512, 512, 512, 2048);
  gemm_t<0, 64, true><<<dim3(8, 32, 4), 256, 0, stream>>>(ffn1, w2bf, b2, proj, 512, 2048, 2048, 512);
  resid_ln<4><<<NN, 256, 0, stream>>>(x2_f32, proj, ln3g, ln3b, (float*)d_out, nullptr);
}